// Round 9
// baseline (149.508 us; speedup 1.0000x reference)
//
#include <hip/hip_runtime.h>
#include <math.h>

// Problem constants
constexpr int B  = 4;
constexpr int S  = 2048;
constexpr int DM = 1024;
constexpr int DK = 128;
constexpr int BS = B * S;
constexpr int NTRI = 528;   // 32*33/2 lower-tri 64x64 tiles

static constexpr float SCALE = 0.08838834764831845f; // 1/sqrt(128)

typedef __attribute__((ext_vector_type(8))) short bf16x8;
typedef __attribute__((ext_vector_type(4))) float f32x4;
typedef __attribute__((ext_vector_type(8))) unsigned short u16x8;

__device__ __forceinline__ unsigned short f2bf(float x) {
  unsigned u = __float_as_uint(x);
  unsigned r = (u + 0x7FFFu + ((u >> 16) & 1u)) >> 16;   // RNE
  return (unsigned short)r;
}
__device__ __forceinline__ float bf2f(unsigned short h) {
  return __uint_as_float(((unsigned)h) << 16);
}

__device__ __forceinline__ void gload16(const void* g, void* l) {
  __builtin_amdgcn_global_load_lds(
      (const __attribute__((address_space(1))) void*)g,
      (__attribute__((address_space(3))) void*)l, 16, 0, 0);
}

// flat lower-tri index -> (qt, st), st <= qt
__device__ __forceinline__ void tri_decode(int i, int& qt, int& st) {
  int q = (int)((sqrtf(8.f * i + 1.f) - 1.f) * 0.5f);
  while ((q + 1) * (q + 2) / 2 <= i) ++q;
  while (q * (q + 1) / 2 > i) --q;
  qt = q;
  st = i - q * (q + 1) / 2;
}

// ---------------------------------------------------------------------------
// Prep 1: vin fp32 -> Ah (bf16 RNE) + Al (bf16 of residual), row-major [BS][DM]
// ---------------------------------------------------------------------------
__global__ __launch_bounds__(256) void cvt_hilo(
    const float* __restrict__ x, unsigned short* __restrict__ hi,
    unsigned short* __restrict__ lo)
{
  const size_t idx = (size_t)blockIdx.x * 256 + threadIdx.x;  // float4 index
  const float4 v = ((const float4*)x)[idx];
  ushort4 h, l;
  h.x = f2bf(v.x); l.x = f2bf(v.x - bf2f(h.x));
  h.y = f2bf(v.y); l.y = f2bf(v.y - bf2f(h.y));
  h.z = f2bf(v.z); l.z = f2bf(v.z - bf2f(h.z));
  h.w = f2bf(v.w); l.w = f2bf(v.w - bf2f(h.w));
  ((ushort4*)hi)[idx] = h;
  ((ushort4*)lo)[idx] = l;
}

// ---------------------------------------------------------------------------
// Prep 2: w_q/w_k/w_v [1024][128] fp32 -> Wt hi/lo bf16 [384][1024] (B^T)
// ---------------------------------------------------------------------------
__global__ void cvtw_kernel(const float* __restrict__ wq, const float* __restrict__ wk,
                            const float* __restrict__ wv,
                            unsigned short* __restrict__ Wth, unsigned short* __restrict__ Wtl)
{
  const int n = blockIdx.x;            // 0..383
  const int p = n >> 7, c = n & 127;
  const float* w = (p == 0) ? wq : (p == 1) ? wk : wv;
  for (int k = threadIdx.x; k < DM; k += 256) {
    const float x = w[(size_t)k * DK + c];
    const unsigned short h = f2bf(x);
    Wth[(size_t)n * DM + k] = h;
    Wtl[(size_t)n * DM + k] = f2bf(x - bf2f(h));
  }
}

// ---------------------------------------------------------------------------
// Kernel A: projections via split-bf16 MFMA. Emits q,k as bf16 hi/lo pairs
// [BS][128] and v as fp32 [BS][128]. XOR-swizzled LDS (T2, src-side).
// ---------------------------------------------------------------------------
__global__ __launch_bounds__(256) void proj_mfma(
    const unsigned short* __restrict__ Ah, const unsigned short* __restrict__ Al,
    const unsigned short* __restrict__ Wh, const unsigned short* __restrict__ Wl,
    unsigned short* __restrict__ qh, unsigned short* __restrict__ ql,
    unsigned short* __restrict__ kh, unsigned short* __restrict__ kl,
    float* __restrict__ vtmp)
{
  __shared__ unsigned short Ash[2][64 * 64];
  __shared__ unsigned short Wsh[2][64 * 64];

  const int r0 = blockIdx.x * 64;      // M tile
  const int n0 = blockIdx.y * 64;      // N tile (384/64 = 6)
  const int t  = threadIdx.x;
  const int l  = t & 63, w = t >> 6;
  const int wm = w >> 1, wn = w & 1;   // 2x2 wave grid
  const int fr = l & 15, kg = l >> 4;  // fragment row / k-group

  f32x4 acc[2][2] = {};

  for (int k0 = 0; k0 < DM; k0 += 64) {
    #pragma unroll
    for (int i = 0; i < 2; ++i) {
      const int flat = t + i * 256;          // 512 16B segments per tile
      const int row = flat >> 3, sg = flat & 7;
      const int sgs = sg ^ (row & 7);        // pre-swizzled source (T2)
      const size_t ga = (size_t)(r0 + row) * DM + k0 + sgs * 8;
      const size_t gw = (size_t)(n0 + row) * DM + k0 + sgs * 8;
      gload16(Ah + ga, &Ash[0][flat * 8]);
      gload16(Al + ga, &Ash[1][flat * 8]);
      gload16(Wh + gw, &Wsh[0][flat * 8]);
      gload16(Wl + gw, &Wsh[1][flat * 8]);
    }
    __syncthreads();

    #pragma unroll
    for (int kk = 0; kk < 2; ++kk) {
      bf16x8 ah[2], al[2], bh[2], bl[2];
      #pragma unroll
      for (int im = 0; im < 2; ++im) {
        const int row = wm * 32 + im * 16 + fr;
        const int off = row * 64 + ((kk * 4 + kg) ^ (row & 7)) * 8;
        ah[im] = *(const bf16x8*)&Ash[0][off];
        al[im] = *(const bf16x8*)&Ash[1][off];
      }
      #pragma unroll
      for (int in = 0; in < 2; ++in) {
        const int row = wn * 32 + in * 16 + fr;
        const int off = row * 64 + ((kk * 4 + kg) ^ (row & 7)) * 8;
        bh[in] = *(const bf16x8*)&Wsh[0][off];
        bl[in] = *(const bf16x8*)&Wsh[1][off];
      }
      #pragma unroll
      for (int im = 0; im < 2; ++im)
        #pragma unroll
        for (int in = 0; in < 2; ++in) {
          acc[im][in] = __builtin_amdgcn_mfma_f32_16x16x32_bf16(ah[im], bh[in], acc[im][in], 0, 0, 0);
          acc[im][in] = __builtin_amdgcn_mfma_f32_16x16x32_bf16(ah[im], bl[in], acc[im][in], 0, 0, 0);
          acc[im][in] = __builtin_amdgcn_mfma_f32_16x16x32_bf16(al[im], bh[in], acc[im][in], 0, 0, 0);
        }
    }
    __syncthreads();
  }

  // Epilogue: C/D layout col = lane&15, row = (lane>>4)*4 + reg
  const int crow = kg * 4;
  #pragma unroll
  for (int im = 0; im < 2; ++im)
    #pragma unroll
    for (int in = 0; in < 2; ++in) {
      const int n = n0 + wn * 32 + in * 16 + fr;
      const int p = n >> 7, c = n & 127;           // p uniform per block
      #pragma unroll
      for (int r = 0; r < 4; ++r) {
        const int m = r0 + wm * 32 + im * 16 + crow + r;
        const float val = acc[im][in][r];
        if (p == 2) {
          vtmp[(size_t)m * DK + c] = val;
        } else {
          const unsigned short h = f2bf(val);
          const unsigned short lo2 = f2bf(val - bf2f(h));
          unsigned short* hd = p ? kh : qh;
          unsigned short* ld = p ? kl : ql;
          hd[(size_t)m * DK + c] = h;
          ld[(size_t)m * DK + c] = lo2;
        }
      }
    }
}

// ---------------------------------------------------------------------------
// Prep 3: transpose v fp32 [B][S][128] -> vT hi/lo bf16 [B][128][S]
// ---------------------------------------------------------------------------
__global__ __launch_bounds__(256) void cvtv_kernel(
    const float* __restrict__ v, unsigned short* __restrict__ vTh,
    unsigned short* __restrict__ vTl)
{
  const int s0 = blockIdx.x * 64, d0 = blockIdx.y * 64, b = blockIdx.z;
  __shared__ float Ts[64][65];
  const int t = threadIdx.x;
  const int r = t >> 4, c4 = (t & 15) * 4;
  #pragma unroll
  for (int rr = 0; rr < 4; ++rr) {
    const int sl = r + 16 * rr;
    *(float4*)&Ts[sl][c4] =
        *(const float4*)&v[((size_t)b * S + s0 + sl) * DK + d0 + c4];
  }
  __syncthreads();
  const int dl = t >> 2, sq = (t & 3) * 16;
  unsigned short hbuf[16], lbuf[16];
  #pragma unroll
  for (int j = 0; j < 16; ++j) {
    const float val = Ts[sq + j][dl];
    hbuf[j] = f2bf(val);
    lbuf[j] = f2bf(val - bf2f(hbuf[j]));
  }
  const size_t o = (size_t)b * DK * S + (size_t)(d0 + dl) * S + s0 + sq;
  #pragma unroll
  for (int half = 0; half < 2; ++half) {
    *(u16x8*)&vTh[o + half * 8] = *(u16x8*)&hbuf[half * 8];
    *(u16x8*)&vTl[o + half * 8] = *(u16x8*)&lbuf[half * 8];
  }
}

// ---------------------------------------------------------------------------
// Kernel B: column-softmax STATS ONLY, tri-only launch. grid (528, B).
// ---------------------------------------------------------------------------
__global__ __launch_bounds__(256) void stats_mfma(
    const unsigned short* __restrict__ qh, const unsigned short* __restrict__ ql,
    const unsigned short* __restrict__ kh, const unsigned short* __restrict__ kl,
    float* __restrict__ pm, float* __restrict__ ps)
{
  int qt, st;
  tri_decode(blockIdx.x, qt, st);
  const int b = blockIdx.y;
  const int q0 = qt * 64, s0 = st * 64;

  __shared__ unsigned short Qh_s[64 * 128], Ql_s[64 * 128];
  __shared__ unsigned short Kh_s[64 * 128], Kl_s[64 * 128];
  __shared__ float SmL[64 * 2], SeL[64 * 2];

  const int t = threadIdx.x;
  const int l = t & 63, w = t >> 6;
  const int wm = w >> 1, wn = w & 1;
  const int fr = l & 15, kg = l >> 4;

  #pragma unroll
  for (int i = 0; i < 4; ++i) {
    const int flat = t + i * 256;
    const int row = flat >> 4, sg = flat & 15;
    const int sgs = sg ^ (row & 7);
    const size_t gq = (size_t)(b * S + q0 + row) * DK + sgs * 8;
    const size_t gk = (size_t)(b * S + s0 + row) * DK + sgs * 8;
    gload16(qh + gq, &Qh_s[flat * 8]);
    gload16(ql + gq, &Ql_s[flat * 8]);
    gload16(kh + gk, &Kh_s[flat * 8]);
    gload16(kl + gk, &Kl_s[flat * 8]);
  }
  __syncthreads();

  f32x4 acc[2][2] = {};
  #pragma unroll
  for (int ks = 0; ks < 4; ++ks) {
    bf16x8 ah[2], al[2], bh[2], bl[2];
    #pragma unroll
    for (int im = 0; im < 2; ++im) {
      const int row = wm * 32 + im * 16 + fr;
      const int off = row * 128 + ((ks * 4 + kg) ^ (row & 7)) * 8;
      ah[im] = *(const bf16x8*)&Qh_s[off];
      al[im] = *(const bf16x8*)&Ql_s[off];
    }
    #pragma unroll
    for (int in = 0; in < 2; ++in) {
      const int row = wn * 32 + in * 16 + fr;
      const int off = row * 128 + ((ks * 4 + kg) ^ (row & 7)) * 8;
      bh[in] = *(const bf16x8*)&Kh_s[off];
      bl[in] = *(const bf16x8*)&Kl_s[off];
    }
    #pragma unroll
    for (int im = 0; im < 2; ++im)
      #pragma unroll
      for (int in = 0; in < 2; ++in) {
        acc[im][in] = __builtin_amdgcn_mfma_f32_16x16x32_bf16(ah[im], bh[in], acc[im][in], 0, 0, 0);
        acc[im][in] = __builtin_amdgcn_mfma_f32_16x16x32_bf16(ah[im], bl[in], acc[im][in], 0, 0, 0);
        acc[im][in] = __builtin_amdgcn_mfma_f32_16x16x32_bf16(al[im], bh[in], acc[im][in], 0, 0, 0);
      }
  }

  // column stats (softmax over q within this 64-row chunk)
  const bool diag = (st == qt);
  float Sm_[2], Se_[2];
  #pragma unroll
  for (int in = 0; in < 2; ++in) {
    const int scol = s0 + wn * 32 + in * 16 + fr;
    float m8 = -INFINITY;
    #pragma unroll
    for (int im = 0; im < 2; ++im)
      #pragma unroll
      for (int r = 0; r < 4; ++r) {
        const int q = q0 + wm * 32 + im * 16 + kg * 4 + r;
        if (!diag || q >= scol) m8 = fmaxf(m8, acc[im][in][r] * SCALE);
      }
    float e8 = 0.f;
    if (m8 > -INFINITY) {
      #pragma unroll
      for (int im = 0; im < 2; ++im)
        #pragma unroll
        for (int r = 0; r < 4; ++r) {
          const int q = q0 + wm * 32 + im * 16 + kg * 4 + r;
          if (!diag || q >= scol) e8 += __expf(acc[im][in][r] * SCALE - m8);
        }
    }
    #pragma unroll
    for (int off = 16; off <= 32; off <<= 1) {
      const float om = __shfl_xor(m8, off);
      const float oe = __shfl_xor(e8, off);
      const float nm = fmaxf(m8, om);
      float ne = 0.f;
      if (m8 > -INFINITY) ne += e8 * __expf(m8 - nm);
      if (om > -INFINITY) ne += oe * __expf(om - nm);
      m8 = nm; e8 = ne;
    }
    Sm_[in] = m8; Se_[in] = e8;
  }
  if (l < 16) {
    #pragma unroll
    for (int in = 0; in < 2; ++in) {
      const int col = wn * 32 + in * 16 + l;
      SmL[col * 2 + wm] = Sm_[in];
      SeL[col * 2 + wm] = Se_[in];
    }
  }
  __syncthreads();
  if (t < 64) {
    const float m0 = SmL[t * 2 + 0], m1 = SmL[t * 2 + 1];
    const float nm = fmaxf(m0, m1);
    float ne = 0.f;
    if (m0 > -INFINITY) ne += SeL[t * 2 + 0] * __expf(m0 - nm);
    if (m1 > -INFINITY) ne += SeL[t * 2 + 1] * __expf(m1 - nm);
    const size_t o = ((size_t)(b * 32 + qt)) * S + s0 + t;
    pm[o] = nm;
    ps[o] = ne;
  }
}

// ---------------------------------------------------------------------------
// Kernel C: combine 32 row-chunk partials -> per-column max m and 1/sum.
// ---------------------------------------------------------------------------
__global__ void colcombine_kernel(const float* __restrict__ pm, const float* __restrict__ ps,
                                  float* __restrict__ cm, float* __restrict__ cinv)
{
  const int s = blockIdx.x * 256 + threadIdx.x;
  const int b = blockIdx.y;
  const int ch0 = s >> 6;
  float m = -INFINITY;
  for (int ch = ch0; ch < 32; ++ch)
    m = fmaxf(m, pm[((size_t)(b * 32 + ch)) * S + s]);
  float sum = 0.f;
  for (int ch = ch0; ch < 32; ++ch) {
    const size_t i = ((size_t)(b * 32 + ch)) * S + s;
    sum += ps[i] * __expf(pm[i] - m);
  }
  cm[(size_t)b * S + s]   = m;
  cinv[(size_t)b * S + s] = 1.f / sum;   // sum >= 1 (diagonal element)
}

// ---------------------------------------------------------------------------
// zero out (out is atomically accumulated)
// ---------------------------------------------------------------------------
__global__ void zero_out_kernel(float* __restrict__ out)
{
  const size_t idx = (size_t)blockIdx.x * 256 + threadIdx.x;
  ((float4*)out)[idx] = float4{0.f, 0.f, 0.f, 0.f};
}

// ---------------------------------------------------------------------------
// zero the strict-upper 64x64 tiles of att. grid (32, 32, B), early-exit.
// One 64x64 tile = 1024 float4 = 4 iterations of 256 threads.
// ---------------------------------------------------------------------------
__global__ __launch_bounds__(256) void zero_upper(float* __restrict__ att)
{
  const int st = blockIdx.x, qt = blockIdx.y, b = blockIdx.z;
  if (st <= qt) return;
  float* attb = att + (size_t)b * S * S + (size_t)qt * 64 * S + st * 64;
  const int t = threadIdx.x;
  const float4 z = {0.f, 0.f, 0.f, 0.f};
  #pragma unroll
  for (int i = 0; i < 4; ++i) {
    const int flat = t + i * 256;          // 0..1023
    const int row = flat >> 4, c4 = (flat & 15) * 4;
    *(float4*)&attb[(size_t)row * S + c4] = z;
  }
}

// ---------------------------------------------------------------------------
// Kernel D: fused second pass, TRI-ONLY. grid (528, B).
// Per 64x64 lower-tri tile: recompute scores (split-bf16 MFMA, same order as
// stats_mfma -> bitwise identical), normalize in-register (cm/cinv + mask),
// P -> LDS bf16 hi/lo, write att fp32 coalesced, PV split-bf16 MFMA,
// atomicAdd to out. LDS time-shared: Q stage -> K tile -> V tile in one
// 32 KB buffer; + P 16 KB = 48 KB -> 3 blocks/CU.
// ---------------------------------------------------------------------------
__global__ __launch_bounds__(256) void fused_pv(
    const unsigned short* __restrict__ qh, const unsigned short* __restrict__ ql,
    const unsigned short* __restrict__ kh, const unsigned short* __restrict__ kl,
    const unsigned short* __restrict__ vTh, const unsigned short* __restrict__ vTl,
    const float* __restrict__ cm, const float* __restrict__ cinv,
    float* __restrict__ att, float* __restrict__ out)
{
  int qt, st;
  tri_decode(blockIdx.x, qt, st);
  const int b = blockIdx.y;
  const int q0 = qt * 64, s0 = st * 64;
  float* attb = att + (size_t)b * S * S;
  const unsigned short* vth = vTh + (size_t)b * DK * S;
  const unsigned short* vtl = vTl + (size_t)b * DK * S;

  __shared__ unsigned short Bsh[64 * 128], Bsl[64 * 128];   // Q stage / K / vT
  __shared__ unsigned short Psh[64 * 64],  Psl[64 * 64];    // P tile

  const int t = threadIdx.x;
  const int l = t & 63, w = t >> 6;
  const int wm = w >> 1, wn = w & 1;          // 2x2 wave grid (scores)
  const int fr = l & 15, kg = l >> 4;
  const int nr = t >> 4, c4 = (t & 15) * 4;   // att-write phase

  // ---- phase 0: stage Q tile, pull fragments to registers ----
  #pragma unroll
  for (int i = 0; i < 4; ++i) {
    const int flat = t + i * 256;
    const int row = flat >> 4, sg = flat & 15;
    const int sgs = sg ^ (row & 7);
    const size_t gq = (size_t)(b * S + q0 + row) * DK + sgs * 8;
    gload16(qh + gq, &Bsh[flat * 8]);
    gload16(ql + gq, &Bsl[flat * 8]);
  }
  __syncthreads();
  bf16x8 qfh[2][4], qfl[2][4];
  #pragma unroll
  for (int im = 0; im < 2; ++im)
    #pragma unroll
    for (int ks = 0; ks < 4; ++ks) {
      const int row = wm * 32 + im * 16 + fr;
      const int off = row * 128 + ((ks * 4 + kg) ^ (row & 7)) * 8;
      qfh[im][ks] = *(const bf16x8*)&Bsh[off];
      qfl[im][ks] = *(const bf16x8*)&Bsl[off];
    }
  __syncthreads();   // all Q reads done before K overwrites

  // ---- phase 1: stage K tile ----
  #pragma unroll
  for (int i = 0; i < 4; ++i) {
    const int flat = t + i * 256;
    const int row = flat >> 4, sg = flat & 15;
    const int sgs = sg ^ (row & 7);
    const size_t gk = (size_t)(b * S + s0 + row) * DK + sgs * 8;
    gload16(kh + gk, &Bsh[flat * 8]);
    gload16(kl + gk, &Bsl[flat * 8]);
  }
  __syncthreads();

  // ---- scores: identical accumulation order to stats_mfma ----
  f32x4 sacc[2][2] = {};
  #pragma unroll
  for (int ks = 0; ks < 4; ++ks) {
    bf16x8 bh[2], bl[2];
    #pragma unroll
    for (int in = 0; in < 2; ++in) {
      const int row = wn * 32 + in * 16 + fr;
      const int off = row * 128 + ((ks * 4 + kg) ^ (row & 7)) * 8;
      bh[in] = *(const bf16x8*)&Bsh[off];
      bl[in] = *(const bf16x8*)&Bsl[off];
    }
    #pragma unroll
    for (int im = 0; im < 2; ++im)
      #pragma unroll
      for (int in = 0; in < 2; ++in) {
        sacc[im][in] = __builtin_amdgcn_mfma_f32_16x16x32_bf16(qfh[im][ks], bh[in], sacc[im][in], 0, 0, 0);
        sacc[im][in] = __builtin_amdgcn_mfma_f32_16x16x32_bf16(qfh[im][ks], bl[in], sacc[im][in], 0, 0, 0);
        sacc[im][in] = __builtin_amdgcn_mfma_f32_16x16x32_bf16(qfl[im][ks], bh[in], sacc[im][in], 0, 0, 0);
      }
  }

  // ---- normalize in-register, push P bf16 hi/lo to LDS ----
  const bool diag = (st == qt);
  #pragma unroll
  for (int im = 0; im < 2; ++im)
    #pragma unroll
    for (int in = 0; in < 2; ++in) {
      const int sloc = wn * 32 + in * 16 + fr;
      const int scol = s0 + sloc;
      const float m   = cm[(size_t)b * S + scol];
      const float inv = cinv[(size_t)b * S + scol];
      #pragma unroll
      for (int r = 0; r < 4; ++r) {
        const int qloc = wm * 32 + im * 16 + kg * 4 + r;
        const bool live = !diag || (q0 + qloc >= scol);
        const float x = live ? __expf(sacc[im][in][r] * SCALE - m) * inv : 0.f;
        const unsigned short hb = f2bf(x);
        const unsigned short lb = f2bf(x - bf2f(hb));
        const int idx = qloc * 64 + (((sloc >> 3) ^ (qloc & 7)) * 8 + (sloc & 7));
        Psh[idx] = hb;
        Psl[idx] = lb;
      }
    }
  __syncthreads();   // K reads done + P complete

  // ---- phase 2: stage vT tile into same buffer; write att from P ----
  #pragma unroll
  for (int i = 0; i < 4; ++i) {
    const int flat = t + i * 256;
    const int row = flat >> 3, sg = flat & 7;
    const int sgs = sg ^ (row & 7);
    const size_t gv = (size_t)row * S + s0 + sgs * 8;
    gload16(vth + gv, &Bsh[flat * 8]);
    gload16(vtl + gv, &Bsl[flat * 8]);
  }
  #pragma unroll
  for (int rr = 0; rr < 4; ++rr) {
    const int qloc = nr + 16 * rr;
    const int idx = qloc * 64 + (((c4 >> 3) ^ (qloc & 7)) * 8 + (c4 & 7));
    float4 x;
    x.x = bf2f(Psh[idx + 0]) + bf2f(Psl[idx + 0]);
    x.y = bf2f(Psh[idx + 1]) + bf2f(Psl[idx + 1]);
    x.z = bf2f(Psh[idx + 2]) + bf2f(Psl[idx + 2]);
    x.w = bf2f(Psh[idx + 3]) + bf2f(Psl[idx + 3]);
    *(float4*)&attb[(size_t)(q0 + qloc) * S + s0 + c4] = x;
  }
  __syncthreads();   // V ready

  // ---- PV: wave w computes q rows [w*16, w*16+16), all 128 d cols ----
  f32x4 acc[8] = {};
  #pragma unroll
  for (int ks2 = 0; ks2 < 2; ++ks2) {
    const int arow = w * 16 + fr;
    const int aoff = arow * 64 + ((ks2 * 4 + kg) ^ (arow & 7)) * 8;
    const bf16x8 a_h = *(const bf16x8*)&Psh[aoff];
    const bf16x8 a_l = *(const bf16x8*)&Psl[aoff];
    #pragma unroll
    for (int in = 0; in < 8; ++in) {
      const int brow = in * 16 + fr;
      const int boff = brow * 64 + ((ks2 * 4 + kg) ^ (brow & 7)) * 8;
      const bf16x8 b_h = *(const bf16x8*)&Bsh[boff];
      const bf16x8 b_l = *(const bf16x8*)&Bsl[boff];
      acc[in] = __builtin_amdgcn_mfma_f32_16x16x32_bf16(a_h, b_h, acc[in], 0, 0, 0);
      acc[in] = __builtin_amdgcn_mfma_f32_16x16x32_bf16(a_h, b_l, acc[in], 0, 0, 0);
      acc[in] = __builtin_amdgcn_mfma_f32_16x16x32_bf16(a_l, b_h, acc[in], 0, 0, 0);
    }
  }

  #pragma unroll
  for (int in = 0; in < 8; ++in) {
    #pragma unroll
    for (int r = 0; r < 4; ++r) {
      const int q = q0 + w * 16 + kg * 4 + r;
      const int d = in * 16 + fr;
      atomicAdd(&out[((size_t)b * S + q) * DK + d], acc[in][r]);
    }
  }
}

// ---------------------------------------------------------------------------
extern "C" void kernel_launch(void* const* d_in, const int* in_sizes, int n_in,
                              void* d_out, int out_size, void* d_ws, size_t ws_size,
                              hipStream_t stream)
{
  const float* vin = (const float*)d_in[0];
  const float* wq  = (const float*)d_in[1];
  const float* wk  = (const float*)d_in[2];
  const float* wv  = (const float*)d_in[3];

  float* out = (float*)d_out;
  float* att = out + (size_t)B * S * DK;     // attention output region (64 MB)

  // bf16 copies of vin / W live INSIDE the att region (dead before att writes)
  unsigned short* Ah  = (unsigned short*)att;
  unsigned short* Al  = Ah  + (size_t)BS * DM;
  unsigned short* Wth = Al  + (size_t)BS * DM;
  unsigned short* Wtl = Wth + (size_t)384 * DM;

  constexpr size_t NE = (size_t)BS * DK;     // 1048576
  unsigned short* qh  = (unsigned short*)d_ws;
  unsigned short* ql  = qh  + NE;
  unsigned short* kh  = ql  + NE;
  unsigned short* kl  = kh  + NE;
  unsigned short* vTh = kl  + NE;
  unsigned short* vTl = vTh + NE;
  float* vtmp = (float*)(vTl + NE);          // 4 MB
  float* pm   = vtmp;                        // aliases vtmp (v dead by then)
  float* ps   = pm + 32ull * B * S;          // 1 MB each
  float* cm   = ps + 32ull * B * S;
  float* cinv = cm + (size_t)B * S;

  cvt_hilo         <<<dim3(BS * DM / 1024),  256, 0, stream>>>(vin, Ah, Al);
  cvtw_kernel      <<<dim3(384),             256, 0, stream>>>(wq, wk, wv, Wth, Wtl);
  proj_mfma        <<<dim3(128, 6),          256, 0, stream>>>(Ah, Al, Wth, Wtl,
                                                               qh, ql, kh, kl, vtmp);
  cvtv_kernel      <<<dim3(S / 64, 2, B),    256, 0, stream>>>(vtmp, vTh, vTl);
  zero_out_kernel  <<<dim3(BS * DK / 1024),  256, 0, stream>>>(out);
  stats_mfma       <<<dim3(NTRI, B),         256, 0, stream>>>(qh, ql, kh, kl, pm, ps);
  colcombine_kernel<<<dim3(S / 256, B),      256, 0, stream>>>(pm, ps, cm, cinv);
  zero_upper       <<<dim3(32, 32, B),       256, 0, stream>>>(att);
  fused_pv         <<<dim3(NTRI, B),         256, 0, stream>>>(qh, ql, kh, kl, vTh, vTl,
                                                               cm, cinv, att, out);
}

// Round 10
// 141.525 us; speedup vs baseline: 1.0564x; 1.0564x over previous
//
#include <hip/hip_runtime.h>
#include <math.h>

// Problem constants
constexpr int B  = 4;
constexpr int S  = 2048;
constexpr int DM = 1024;
constexpr int DK = 128;
constexpr int BS = B * S;
constexpr int NTRI = 528;   // 32*33/2 lower-tri 64x64 tiles

static constexpr float SCALE = 0.08838834764831845f; // 1/sqrt(128)

typedef __attribute__((ext_vector_type(8))) short bf16x8;
typedef __attribute__((ext_vector_type(4))) float f32x4;
typedef __attribute__((ext_vector_type(8))) unsigned short u16x8;

__device__ __forceinline__ unsigned short f2bf(float x) {
  unsigned u = __float_as_uint(x);
  unsigned r = (u + 0x7FFFu + ((u >> 16) & 1u)) >> 16;   // RNE
  return (unsigned short)r;
}
__device__ __forceinline__ float bf2f(unsigned short h) {
  return __uint_as_float(((unsigned)h) << 16);
}

__device__ __forceinline__ void gload16(const void* g, void* l) {
  __builtin_amdgcn_global_load_lds(
      (const __attribute__((address_space(1))) void*)g,
      (__attribute__((address_space(3))) void*)l, 16, 0, 0);
}

// flat lower-tri index -> (qt, st), st <= qt
__device__ __forceinline__ void tri_decode(int i, int& qt, int& st) {
  int q = (int)((sqrtf(8.f * i + 1.f) - 1.f) * 0.5f);
  while ((q + 1) * (q + 2) / 2 <= i) ++q;
  while (q * (q + 1) / 2 > i) --q;
  qt = q;
  st = i - q * (q + 1) / 2;
}

// ---------------------------------------------------------------------------
// Prep 1: vin fp32 -> Ah (bf16 RNE) + Al (bf16 of residual), row-major [BS][DM]
// ---------------------------------------------------------------------------
__global__ __launch_bounds__(256) void cvt_hilo(
    const float* __restrict__ x, unsigned short* __restrict__ hi,
    unsigned short* __restrict__ lo)
{
  const size_t idx = (size_t)blockIdx.x * 256 + threadIdx.x;  // float4 index
  const float4 v = ((const float4*)x)[idx];
  ushort4 h, l;
  h.x = f2bf(v.x); l.x = f2bf(v.x - bf2f(h.x));
  h.y = f2bf(v.y); l.y = f2bf(v.y - bf2f(h.y));
  h.z = f2bf(v.z); l.z = f2bf(v.z - bf2f(h.z));
  h.w = f2bf(v.w); l.w = f2bf(v.w - bf2f(h.w));
  ((ushort4*)hi)[idx] = h;
  ((ushort4*)lo)[idx] = l;
}

// ---------------------------------------------------------------------------
// Prep 2: w_q/w_k/w_v [1024][128] fp32 -> Wt hi/lo bf16 [384][1024] (B^T)
// ---------------------------------------------------------------------------
__global__ void cvtw_kernel(const float* __restrict__ wq, const float* __restrict__ wk,
                            const float* __restrict__ wv,
                            unsigned short* __restrict__ Wth, unsigned short* __restrict__ Wtl)
{
  const int n = blockIdx.x;            // 0..383
  const int p = n >> 7, c = n & 127;
  const float* w = (p == 0) ? wq : (p == 1) ? wk : wv;
  for (int k = threadIdx.x; k < DM; k += 256) {
    const float x = w[(size_t)k * DK + c];
    const unsigned short h = f2bf(x);
    Wth[(size_t)n * DM + k] = h;
    Wtl[(size_t)n * DM + k] = f2bf(x - bf2f(h));
  }
}

// ---------------------------------------------------------------------------
// Kernel A: projections via split-bf16 MFMA. Emits q,k as bf16 hi/lo pairs
// [BS][128] and v as fp32 [BS][128]. XOR-swizzled LDS (T2, src-side).
// ---------------------------------------------------------------------------
__global__ __launch_bounds__(256) void proj_mfma(
    const unsigned short* __restrict__ Ah, const unsigned short* __restrict__ Al,
    const unsigned short* __restrict__ Wh, const unsigned short* __restrict__ Wl,
    unsigned short* __restrict__ qh, unsigned short* __restrict__ ql,
    unsigned short* __restrict__ kh, unsigned short* __restrict__ kl,
    float* __restrict__ vtmp)
{
  __shared__ unsigned short Ash[2][64 * 64];
  __shared__ unsigned short Wsh[2][64 * 64];

  const int r0 = blockIdx.x * 64;      // M tile
  const int n0 = blockIdx.y * 64;      // N tile (384/64 = 6)
  const int t  = threadIdx.x;
  const int l  = t & 63, w = t >> 6;
  const int wm = w >> 1, wn = w & 1;   // 2x2 wave grid
  const int fr = l & 15, kg = l >> 4;  // fragment row / k-group

  f32x4 acc[2][2] = {};

  for (int k0 = 0; k0 < DM; k0 += 64) {
    #pragma unroll
    for (int i = 0; i < 2; ++i) {
      const int flat = t + i * 256;          // 512 16B segments per tile
      const int row = flat >> 3, sg = flat & 7;
      const int sgs = sg ^ (row & 7);        // pre-swizzled source (T2)
      const size_t ga = (size_t)(r0 + row) * DM + k0 + sgs * 8;
      const size_t gw = (size_t)(n0 + row) * DM + k0 + sgs * 8;
      gload16(Ah + ga, &Ash[0][flat * 8]);
      gload16(Al + ga, &Ash[1][flat * 8]);
      gload16(Wh + gw, &Wsh[0][flat * 8]);
      gload16(Wl + gw, &Wsh[1][flat * 8]);
    }
    __syncthreads();

    #pragma unroll
    for (int kk = 0; kk < 2; ++kk) {
      bf16x8 ah[2], al[2], bh[2], bl[2];
      #pragma unroll
      for (int im = 0; im < 2; ++im) {
        const int row = wm * 32 + im * 16 + fr;
        const int off = row * 64 + ((kk * 4 + kg) ^ (row & 7)) * 8;
        ah[im] = *(const bf16x8*)&Ash[0][off];
        al[im] = *(const bf16x8*)&Ash[1][off];
      }
      #pragma unroll
      for (int in = 0; in < 2; ++in) {
        const int row = wn * 32 + in * 16 + fr;
        const int off = row * 64 + ((kk * 4 + kg) ^ (row & 7)) * 8;
        bh[in] = *(const bf16x8*)&Wsh[0][off];
        bl[in] = *(const bf16x8*)&Wsh[1][off];
      }
      #pragma unroll
      for (int im = 0; im < 2; ++im)
        #pragma unroll
        for (int in = 0; in < 2; ++in) {
          acc[im][in] = __builtin_amdgcn_mfma_f32_16x16x32_bf16(ah[im], bh[in], acc[im][in], 0, 0, 0);
          acc[im][in] = __builtin_amdgcn_mfma_f32_16x16x32_bf16(ah[im], bl[in], acc[im][in], 0, 0, 0);
          acc[im][in] = __builtin_amdgcn_mfma_f32_16x16x32_bf16(al[im], bh[in], acc[im][in], 0, 0, 0);
        }
    }
    __syncthreads();
  }

  // Epilogue: C/D layout col = lane&15, row = (lane>>4)*4 + reg
  const int crow = kg * 4;
  #pragma unroll
  for (int im = 0; im < 2; ++im)
    #pragma unroll
    for (int in = 0; in < 2; ++in) {
      const int n = n0 + wn * 32 + in * 16 + fr;
      const int p = n >> 7, c = n & 127;           // p uniform per block
      #pragma unroll
      for (int r = 0; r < 4; ++r) {
        const int m = r0 + wm * 32 + im * 16 + crow + r;
        const float val = acc[im][in][r];
        if (p == 2) {
          vtmp[(size_t)m * DK + c] = val;
        } else {
          const unsigned short h = f2bf(val);
          const unsigned short lo2 = f2bf(val - bf2f(h));
          unsigned short* hd = p ? kh : qh;
          unsigned short* ld = p ? kl : ql;
          hd[(size_t)m * DK + c] = h;
          ld[(size_t)m * DK + c] = lo2;
        }
      }
    }
}

// ---------------------------------------------------------------------------
// Prep 3: transpose v fp32 [B][S][128] -> vT hi/lo bf16 [B][128][S]
// ---------------------------------------------------------------------------
__global__ __launch_bounds__(256) void cvtv_kernel(
    const float* __restrict__ v, unsigned short* __restrict__ vTh,
    unsigned short* __restrict__ vTl)
{
  const int s0 = blockIdx.x * 64, d0 = blockIdx.y * 64, b = blockIdx.z;
  __shared__ float Ts[64][65];
  const int t = threadIdx.x;
  const int r = t >> 4, c4 = (t & 15) * 4;
  #pragma unroll
  for (int rr = 0; rr < 4; ++rr) {
    const int sl = r + 16 * rr;
    *(float4*)&Ts[sl][c4] =
        *(const float4*)&v[((size_t)b * S + s0 + sl) * DK + d0 + c4];
  }
  __syncthreads();
  const int dl = t >> 2, sq = (t & 3) * 16;
  unsigned short hbuf[16], lbuf[16];
  #pragma unroll
  for (int j = 0; j < 16; ++j) {
    const float val = Ts[sq + j][dl];
    hbuf[j] = f2bf(val);
    lbuf[j] = f2bf(val - bf2f(hbuf[j]));
  }
  const size_t o = (size_t)b * DK * S + (size_t)(d0 + dl) * S + s0 + sq;
  #pragma unroll
  for (int half = 0; half < 2; ++half) {
    *(u16x8*)&vTh[o + half * 8] = *(u16x8*)&hbuf[half * 8];
    *(u16x8*)&vTl[o + half * 8] = *(u16x8*)&lbuf[half * 8];
  }
}

// ---------------------------------------------------------------------------
// Kernel B: column-softmax STATS ONLY, tri-only launch. grid (528, B).
// LDS time-share: Q staged -> frags to regs -> K into same 32 KB buffer.
// ---------------------------------------------------------------------------
__global__ __launch_bounds__(256) void stats_mfma(
    const unsigned short* __restrict__ qh, const unsigned short* __restrict__ ql,
    const unsigned short* __restrict__ kh, const unsigned short* __restrict__ kl,
    float* __restrict__ pm, float* __restrict__ ps)
{
  int qt, st;
  tri_decode(blockIdx.x, qt, st);
  const int b = blockIdx.y;
  const int q0 = qt * 64, s0 = st * 64;

  __shared__ unsigned short Bsh[64 * 128], Bsl[64 * 128];   // Q stage / K
  __shared__ float SmL[64 * 2], SeL[64 * 2];

  const int t = threadIdx.x;
  const int l = t & 63, w = t >> 6;
  const int wm = w >> 1, wn = w & 1;
  const int fr = l & 15, kg = l >> 4;

  // ---- phase 0: stage Q, pull fragments to registers ----
  #pragma unroll
  for (int i = 0; i < 4; ++i) {
    const int flat = t + i * 256;
    const int row = flat >> 4, sg = flat & 15;
    const int sgs = sg ^ (row & 7);
    const size_t gq = (size_t)(b * S + q0 + row) * DK + sgs * 8;
    gload16(qh + gq, &Bsh[flat * 8]);
    gload16(ql + gq, &Bsl[flat * 8]);
  }
  __syncthreads();
  bf16x8 qfh[2][4], qfl[2][4];
  #pragma unroll
  for (int im = 0; im < 2; ++im)
    #pragma unroll
    for (int ks = 0; ks < 4; ++ks) {
      const int row = wm * 32 + im * 16 + fr;
      const int off = row * 128 + ((ks * 4 + kg) ^ (row & 7)) * 8;
      qfh[im][ks] = *(const bf16x8*)&Bsh[off];
      qfl[im][ks] = *(const bf16x8*)&Bsl[off];
    }
  __syncthreads();   // Q reads done before K overwrites

  // ---- phase 1: stage K ----
  #pragma unroll
  for (int i = 0; i < 4; ++i) {
    const int flat = t + i * 256;
    const int row = flat >> 4, sg = flat & 15;
    const int sgs = sg ^ (row & 7);
    const size_t gk = (size_t)(b * S + s0 + row) * DK + sgs * 8;
    gload16(kh + gk, &Bsh[flat * 8]);
    gload16(kl + gk, &Bsl[flat * 8]);
  }
  __syncthreads();

  // ---- scores (order must match fused_pv exactly) ----
  f32x4 acc[2][2] = {};
  #pragma unroll
  for (int ks = 0; ks < 4; ++ks) {
    bf16x8 bh[2], bl[2];
    #pragma unroll
    for (int in = 0; in < 2; ++in) {
      const int row = wn * 32 + in * 16 + fr;
      const int off = row * 128 + ((ks * 4 + kg) ^ (row & 7)) * 8;
      bh[in] = *(const bf16x8*)&Bsh[off];
      bl[in] = *(const bf16x8*)&Bsl[off];
    }
    #pragma unroll
    for (int im = 0; im < 2; ++im)
      #pragma unroll
      for (int in = 0; in < 2; ++in) {
        acc[im][in] = __builtin_amdgcn_mfma_f32_16x16x32_bf16(qfh[im][ks], bh[in], acc[im][in], 0, 0, 0);
        acc[im][in] = __builtin_amdgcn_mfma_f32_16x16x32_bf16(qfh[im][ks], bl[in], acc[im][in], 0, 0, 0);
        acc[im][in] = __builtin_amdgcn_mfma_f32_16x16x32_bf16(qfl[im][ks], bh[in], acc[im][in], 0, 0, 0);
      }
  }

  // column stats (softmax over q within this 64-row chunk)
  const bool diag = (st == qt);
  float Sm_[2], Se_[2];
  #pragma unroll
  for (int in = 0; in < 2; ++in) {
    const int scol = s0 + wn * 32 + in * 16 + fr;
    float m8 = -INFINITY;
    #pragma unroll
    for (int im = 0; im < 2; ++im)
      #pragma unroll
      for (int r = 0; r < 4; ++r) {
        const int q = q0 + wm * 32 + im * 16 + kg * 4 + r;
        if (!diag || q >= scol) m8 = fmaxf(m8, acc[im][in][r] * SCALE);
      }
    float e8 = 0.f;
    if (m8 > -INFINITY) {
      #pragma unroll
      for (int im = 0; im < 2; ++im)
        #pragma unroll
        for (int r = 0; r < 4; ++r) {
          const int q = q0 + wm * 32 + im * 16 + kg * 4 + r;
          if (!diag || q >= scol) e8 += __expf(acc[im][in][r] * SCALE - m8);
        }
    }
    #pragma unroll
    for (int off = 16; off <= 32; off <<= 1) {
      const float om = __shfl_xor(m8, off);
      const float oe = __shfl_xor(e8, off);
      const float nm = fmaxf(m8, om);
      float ne = 0.f;
      if (m8 > -INFINITY) ne += e8 * __expf(m8 - nm);
      if (om > -INFINITY) ne += oe * __expf(om - nm);
      m8 = nm; e8 = ne;
    }
    Sm_[in] = m8; Se_[in] = e8;
  }
  if (l < 16) {
    #pragma unroll
    for (int in = 0; in < 2; ++in) {
      const int col = wn * 32 + in * 16 + l;
      SmL[col * 2 + wm] = Sm_[in];
      SeL[col * 2 + wm] = Se_[in];
    }
  }
  __syncthreads();
  if (t < 64) {
    const float m0 = SmL[t * 2 + 0], m1 = SmL[t * 2 + 1];
    const float nm = fmaxf(m0, m1);
    float ne = 0.f;
    if (m0 > -INFINITY) ne += SeL[t * 2 + 0] * __expf(m0 - nm);
    if (m1 > -INFINITY) ne += SeL[t * 2 + 1] * __expf(m1 - nm);
    const size_t o = ((size_t)(b * 32 + qt)) * S + s0 + t;
    pm[o] = nm;
    ps[o] = ne;
  }
}

// ---------------------------------------------------------------------------
// Kernel C: combine 32 row-chunk partials -> per-column max m and 1/sum.
// ---------------------------------------------------------------------------
__global__ void colcombine_kernel(const float* __restrict__ pm, const float* __restrict__ ps,
                                  float* __restrict__ cm, float* __restrict__ cinv)
{
  const int s = blockIdx.x * 256 + threadIdx.x;
  const int b = blockIdx.y;
  const int ch0 = s >> 6;
  float m = -INFINITY;
  for (int ch = ch0; ch < 32; ++ch)
    m = fmaxf(m, pm[((size_t)(b * 32 + ch)) * S + s]);
  float sum = 0.f;
  for (int ch = ch0; ch < 32; ++ch) {
    const size_t i = ((size_t)(b * 32 + ch)) * S + s;
    sum += ps[i] * __expf(pm[i] - m);
  }
  cm[(size_t)b * S + s]   = m;
  cinv[(size_t)b * S + s] = 1.f / sum;   // sum >= 1 (diagonal element)
}

// ---------------------------------------------------------------------------
// zero out (out is atomically accumulated)
// ---------------------------------------------------------------------------
__global__ void zero_out_kernel(float* __restrict__ out)
{
  const size_t idx = (size_t)blockIdx.x * 256 + threadIdx.x;
  ((float4*)out)[idx] = float4{0.f, 0.f, 0.f, 0.f};
}

// ---------------------------------------------------------------------------
// Kernel D: fused second pass, TRI-ONLY. grid (528, B).
// Recompute scores (bitwise-identical to stats_mfma), normalize in-register,
// att written directly from registers (fp32), P kept as PLAIN bf16 in LDS
// (8 KB), PV = P x (Vh+Vl) MFMA, atomicAdd epilogue. Off-diagonal blocks also
// zero their mirror (strict-upper) att tile. LDS 40 KB -> 4 blocks/CU.
// ---------------------------------------------------------------------------
__global__ __launch_bounds__(256) void fused_pv(
    const unsigned short* __restrict__ qh, const unsigned short* __restrict__ ql,
    const unsigned short* __restrict__ kh, const unsigned short* __restrict__ kl,
    const unsigned short* __restrict__ vTh, const unsigned short* __restrict__ vTl,
    const float* __restrict__ cm, const float* __restrict__ cinv,
    float* __restrict__ att, float* __restrict__ out)
{
  int qt, st;
  tri_decode(blockIdx.x, qt, st);
  const int b = blockIdx.y;
  const int q0 = qt * 64, s0 = st * 64;
  float* attb = att + (size_t)b * S * S;
  const unsigned short* vth = vTh + (size_t)b * DK * S;
  const unsigned short* vtl = vTl + (size_t)b * DK * S;

  __shared__ unsigned short Bsh[64 * 128], Bsl[64 * 128];   // Q stage / K / vT
  __shared__ unsigned short Psh[64 * 64];                   // P tile (plain bf16)

  const int t = threadIdx.x;
  const int l = t & 63, w = t >> 6;
  const int wm = w >> 1, wn = w & 1;          // 2x2 wave grid (scores)
  const int fr = l & 15, kg = l >> 4;

  // ---- phase 0: stage Q tile, pull fragments to registers ----
  #pragma unroll
  for (int i = 0; i < 4; ++i) {
    const int flat = t + i * 256;
    const int row = flat >> 4, sg = flat & 15;
    const int sgs = sg ^ (row & 7);
    const size_t gq = (size_t)(b * S + q0 + row) * DK + sgs * 8;
    gload16(qh + gq, &Bsh[flat * 8]);
    gload16(ql + gq, &Bsl[flat * 8]);
  }
  __syncthreads();
  bf16x8 qfh[2][4], qfl[2][4];
  #pragma unroll
  for (int im = 0; im < 2; ++im)
    #pragma unroll
    for (int ks = 0; ks < 4; ++ks) {
      const int row = wm * 32 + im * 16 + fr;
      const int off = row * 128 + ((ks * 4 + kg) ^ (row & 7)) * 8;
      qfh[im][ks] = *(const bf16x8*)&Bsh[off];
      qfl[im][ks] = *(const bf16x8*)&Bsl[off];
    }
  __syncthreads();   // all Q reads done before K overwrites

  // ---- phase 1: stage K tile ----
  #pragma unroll
  for (int i = 0; i < 4; ++i) {
    const int flat = t + i * 256;
    const int row = flat >> 4, sg = flat & 15;
    const int sgs = sg ^ (row & 7);
    const size_t gk = (size_t)(b * S + s0 + row) * DK + sgs * 8;
    gload16(kh + gk, &Bsh[flat * 8]);
    gload16(kl + gk, &Bsl[flat * 8]);
  }
  __syncthreads();

  // ---- scores: identical accumulation order to stats_mfma ----
  f32x4 sacc[2][2] = {};
  #pragma unroll
  for (int ks = 0; ks < 4; ++ks) {
    bf16x8 bh[2], bl[2];
    #pragma unroll
    for (int in = 0; in < 2; ++in) {
      const int row = wn * 32 + in * 16 + fr;
      const int off = row * 128 + ((ks * 4 + kg) ^ (row & 7)) * 8;
      bh[in] = *(const bf16x8*)&Bsh[off];
      bl[in] = *(const bf16x8*)&Bsl[off];
    }
    #pragma unroll
    for (int im = 0; im < 2; ++im)
      #pragma unroll
      for (int in = 0; in < 2; ++in) {
        sacc[im][in] = __builtin_amdgcn_mfma_f32_16x16x32_bf16(qfh[im][ks], bh[in], sacc[im][in], 0, 0, 0);
        sacc[im][in] = __builtin_amdgcn_mfma_f32_16x16x32_bf16(qfh[im][ks], bl[in], sacc[im][in], 0, 0, 0);
        sacc[im][in] = __builtin_amdgcn_mfma_f32_16x16x32_bf16(qfl[im][ks], bh[in], sacc[im][in], 0, 0, 0);
      }
  }

  // ---- normalize in-register; P (plain bf16) -> LDS; keep x in regs ----
  const bool diag = (st == qt);
  float xv[2][2][4];
  #pragma unroll
  for (int in = 0; in < 2; ++in) {
    const int sloc = wn * 32 + in * 16 + fr;
    const int scol = s0 + sloc;
    const float m   = cm[(size_t)b * S + scol];
    const float inv = cinv[(size_t)b * S + scol];
    #pragma unroll
    for (int im = 0; im < 2; ++im) {
      #pragma unroll
      for (int r = 0; r < 4; ++r) {
        const int qloc = wm * 32 + im * 16 + kg * 4 + r;
        const bool live = !diag || (q0 + qloc >= scol);
        const float x = live ? __expf(sacc[im][in][r] * SCALE - m) * inv : 0.f;
        xv[im][in][r] = x;
        const int idx = qloc * 64 + (((sloc >> 3) ^ (qloc & 7)) * 8 + (sloc & 7));
        Psh[idx] = f2bf(x);
      }
    }
  }
  __syncthreads();   // K reads done + P complete

  // ---- phase 2: issue vT staging (latency hidden under stores below) ----
  #pragma unroll
  for (int i = 0; i < 4; ++i) {
    const int flat = t + i * 256;
    const int row = flat >> 3, sg = flat & 7;
    const int sgs = sg ^ (row & 7);
    const size_t gv = (size_t)row * S + s0 + sgs * 8;
    gload16(vth + gv, &Bsh[flat * 8]);
    gload16(vtl + gv, &Bsl[flat * 8]);
  }

  // mirror (strict-upper) tile zeroing: rows s0.., cols q0..
  if (st < qt) {
    const float4 z = {0.f, 0.f, 0.f, 0.f};
    #pragma unroll
    for (int i = 0; i < 4; ++i) {
      const int flat = t + i * 256;          // 0..1023
      const int row = flat >> 4, c4 = (flat & 15) * 4;
      *(float4*)&attb[(size_t)(s0 + row) * S + q0 + c4] = z;
    }
  }

  // att writes from registers (fp32, exact normalized values)
  #pragma unroll
  for (int im = 0; im < 2; ++im)
    #pragma unroll
    for (int in = 0; in < 2; ++in) {
      const int sloc = wn * 32 + in * 16 + fr;
      #pragma unroll
      for (int r = 0; r < 4; ++r) {
        const int qloc = wm * 32 + im * 16 + kg * 4 + r;
        attb[(size_t)(q0 + qloc) * S + s0 + sloc] = xv[im][in][r];
      }
    }
  __syncthreads();   // V ready

  // ---- PV: wave w computes q rows [w*16, w*16+16), all 128 d cols ----
  f32x4 acc[8] = {};
  #pragma unroll
  for (int ks2 = 0; ks2 < 2; ++ks2) {
    const int arow = w * 16 + fr;
    const int aoff = arow * 64 + ((ks2 * 4 + kg) ^ (arow & 7)) * 8;
    const bf16x8 a = *(const bf16x8*)&Psh[aoff];
    #pragma unroll
    for (int in = 0; in < 8; ++in) {
      const int brow = in * 16 + fr;
      const int boff = brow * 64 + ((ks2 * 4 + kg) ^ (brow & 7)) * 8;
      const bf16x8 b_h = *(const bf16x8*)&Bsh[boff];
      const bf16x8 b_l = *(const bf16x8*)&Bsl[boff];
      acc[in] = __builtin_amdgcn_mfma_f32_16x16x32_bf16(a, b_h, acc[in], 0, 0, 0);
      acc[in] = __builtin_amdgcn_mfma_f32_16x16x32_bf16(a, b_l, acc[in], 0, 0, 0);
    }
  }

  #pragma unroll
  for (int in = 0; in < 8; ++in) {
    #pragma unroll
    for (int r = 0; r < 4; ++r) {
      const int q = q0 + w * 16 + kg * 4 + r;
      const int d = in * 16 + fr;
      atomicAdd(&out[((size_t)b * S + q) * DK + d], acc[in][r]);
    }
  }
}

// ---------------------------------------------------------------------------
extern "C" void kernel_launch(void* const* d_in, const int* in_sizes, int n_in,
                              void* d_out, int out_size, void* d_ws, size_t ws_size,
                              hipStream_t stream)
{
  const float* vin = (const float*)d_in[0];
  const float* wq  = (const float*)d_in[1];
  const float* wk  = (const float*)d_in[2];
  const float* wv  = (const float*)d_in[3];

  float* out = (float*)d_out;
  float* att = out + (size_t)B * S * DK;     // attention output region (64 MB)

  // bf16 copies of vin / W live INSIDE the att region (dead before att writes)
  unsigned short* Ah  = (unsigned short*)att;
  unsigned short* Al  = Ah  + (size_t)BS * DM;
  unsigned short* Wth = Al  + (size_t)BS * DM;
  unsigned short* Wtl = Wth + (size_t)384 * DM;

  constexpr size_t NE = (size_t)BS * DK;     // 1048576
  unsigned short* qh  = (unsigned short*)d_ws;
  unsigned short* ql  = qh  + NE;
  unsigned short* kh  = ql  + NE;
  unsigned short* kl  = kh  + NE;
  unsigned short* vTh = kl  + NE;
  unsigned short* vTl = vTh + NE;
  float* vtmp = (float*)(vTl + NE);          // 4 MB
  float* pm   = vtmp;                        // aliases vtmp (v dead by then)
  float* ps   = pm + 32ull * B * S;          // 1 MB each
  float* cm   = ps + 32ull * B * S;
  float* cinv = cm + (size_t)B * S;

  cvt_hilo         <<<dim3(BS * DM / 1024),  256, 0, stream>>>(vin, Ah, Al);
  cvtw_kernel      <<<dim3(384),             256, 0, stream>>>(wq, wk, wv, Wth, Wtl);
  proj_mfma        <<<dim3(128, 6),          256, 0, stream>>>(Ah, Al, Wth, Wtl,
                                                               qh, ql, kh, kl, vtmp);
  cvtv_kernel      <<<dim3(S / 64, 2, B),    256, 0, stream>>>(vtmp, vTh, vTl);
  zero_out_kernel  <<<dim3(BS * DK / 1024),  256, 0, stream>>>(out);
  stats_mfma       <<<dim3(NTRI, B),         256, 0, stream>>>(qh, ql, kh, kl, pm, ps);
  colcombine_kernel<<<dim3(S / 256, B),      256, 0, stream>>>(pm, ps, cm, cinv);
  fused_pv         <<<dim3(NTRI, B),         256, 0, stream>>>(qh, ql, kh, kl, vTh, vTl,
                                                               cm, cinv, att, out);
}

// Round 11
// 117.864 us; speedup vs baseline: 1.2685x; 1.2007x over previous
//
#include <hip/hip_runtime.h>
#include <math.h>

// Problem constants
constexpr int B  = 4;
constexpr int S  = 2048;
constexpr int DM = 1024;
constexpr int DK = 128;
constexpr int BS = B * S;
constexpr int NSP = 8;      // st-split factor (contention <= 8-way)

static constexpr float SCALE = 0.08838834764831845f; // 1/sqrt(128)

typedef __attribute__((ext_vector_type(8))) short bf16x8;
typedef __attribute__((ext_vector_type(4))) float f32x4;
typedef __attribute__((ext_vector_type(8))) unsigned short u16x8;

__device__ __forceinline__ unsigned short f2bf(float x) {
  unsigned u = __float_as_uint(x);
  unsigned r = (u + 0x7FFFu + ((u >> 16) & 1u)) >> 16;   // RNE
  return (unsigned short)r;
}
__device__ __forceinline__ float bf2f(unsigned short h) {
  return __uint_as_float(((unsigned)h) << 16);
}

__device__ __forceinline__ void gload16(const void* g, void* l) {
  __builtin_amdgcn_global_load_lds(
      (const __attribute__((address_space(1))) void*)g,
      (__attribute__((address_space(3))) void*)l, 16, 0, 0);
}

// ---------------------------------------------------------------------------
// Prep 1: vin fp32 -> Ah (bf16 RNE) + Al (bf16 of residual), row-major [BS][DM]
// ---------------------------------------------------------------------------
__global__ __launch_bounds__(256) void cvt_hilo(
    const float* __restrict__ x, unsigned short* __restrict__ hi,
    unsigned short* __restrict__ lo)
{
  const size_t idx = (size_t)blockIdx.x * 256 + threadIdx.x;  // float4 index
  const float4 v = ((const float4*)x)[idx];
  ushort4 h, l;
  h.x = f2bf(v.x); l.x = f2bf(v.x - bf2f(h.x));
  h.y = f2bf(v.y); l.y = f2bf(v.y - bf2f(h.y));
  h.z = f2bf(v.z); l.z = f2bf(v.z - bf2f(h.z));
  h.w = f2bf(v.w); l.w = f2bf(v.w - bf2f(h.w));
  ((ushort4*)hi)[idx] = h;
  ((ushort4*)lo)[idx] = l;
}

// ---------------------------------------------------------------------------
// Prep 2: w_q/w_k/w_v [1024][128] fp32 -> Wt hi/lo bf16 [384][1024] (B^T)
// ---------------------------------------------------------------------------
__global__ void cvtw_kernel(const float* __restrict__ wq, const float* __restrict__ wk,
                            const float* __restrict__ wv,
                            unsigned short* __restrict__ Wth, unsigned short* __restrict__ Wtl)
{
  const int n = blockIdx.x;            // 0..383
  const int p = n >> 7, c = n & 127;
  const float* w = (p == 0) ? wq : (p == 1) ? wk : wv;
  for (int k = threadIdx.x; k < DM; k += 256) {
    const float x = w[(size_t)k * DK + c];
    const unsigned short h = f2bf(x);
    Wth[(size_t)n * DM + k] = h;
    Wtl[(size_t)n * DM + k] = f2bf(x - bf2f(h));
  }
}

// ---------------------------------------------------------------------------
// Kernel A: projections via split-bf16 MFMA. Emits q,k as bf16 hi/lo pairs
// [BS][128] and v as fp32 [BS][128]. XOR-swizzled LDS (T2, src-side).
// ---------------------------------------------------------------------------
__global__ __launch_bounds__(256) void proj_mfma(
    const unsigned short* __restrict__ Ah, const unsigned short* __restrict__ Al,
    const unsigned short* __restrict__ Wh, const unsigned short* __restrict__ Wl,
    unsigned short* __restrict__ qh, unsigned short* __restrict__ ql,
    unsigned short* __restrict__ kh, unsigned short* __restrict__ kl,
    float* __restrict__ vtmp)
{
  __shared__ unsigned short Ash[2][64 * 64];
  __shared__ unsigned short Wsh[2][64 * 64];

  const int r0 = blockIdx.x * 64;      // M tile
  const int n0 = blockIdx.y * 64;      // N tile (384/64 = 6)
  const int t  = threadIdx.x;
  const int l  = t & 63, w = t >> 6;
  const int wm = w >> 1, wn = w & 1;   // 2x2 wave grid
  const int fr = l & 15, kg = l >> 4;  // fragment row / k-group

  f32x4 acc[2][2] = {};

  for (int k0 = 0; k0 < DM; k0 += 64) {
    #pragma unroll
    for (int i = 0; i < 2; ++i) {
      const int flat = t + i * 256;          // 512 16B segments per tile
      const int row = flat >> 3, sg = flat & 7;
      const int sgs = sg ^ (row & 7);        // pre-swizzled source (T2)
      const size_t ga = (size_t)(r0 + row) * DM + k0 + sgs * 8;
      const size_t gw = (size_t)(n0 + row) * DM + k0 + sgs * 8;
      gload16(Ah + ga, &Ash[0][flat * 8]);
      gload16(Al + ga, &Ash[1][flat * 8]);
      gload16(Wh + gw, &Wsh[0][flat * 8]);
      gload16(Wl + gw, &Wsh[1][flat * 8]);
    }
    __syncthreads();

    #pragma unroll
    for (int kk = 0; kk < 2; ++kk) {
      bf16x8 ah[2], al[2], bh[2], bl[2];
      #pragma unroll
      for (int im = 0; im < 2; ++im) {
        const int row = wm * 32 + im * 16 + fr;
        const int off = row * 64 + ((kk * 4 + kg) ^ (row & 7)) * 8;
        ah[im] = *(const bf16x8*)&Ash[0][off];
        al[im] = *(const bf16x8*)&Ash[1][off];
      }
      #pragma unroll
      for (int in = 0; in < 2; ++in) {
        const int row = wn * 32 + in * 16 + fr;
        const int off = row * 64 + ((kk * 4 + kg) ^ (row & 7)) * 8;
        bh[in] = *(const bf16x8*)&Wsh[0][off];
        bl[in] = *(const bf16x8*)&Wsh[1][off];
      }
      #pragma unroll
      for (int im = 0; im < 2; ++im)
        #pragma unroll
        for (int in = 0; in < 2; ++in) {
          acc[im][in] = __builtin_amdgcn_mfma_f32_16x16x32_bf16(ah[im], bh[in], acc[im][in], 0, 0, 0);
          acc[im][in] = __builtin_amdgcn_mfma_f32_16x16x32_bf16(ah[im], bl[in], acc[im][in], 0, 0, 0);
          acc[im][in] = __builtin_amdgcn_mfma_f32_16x16x32_bf16(al[im], bh[in], acc[im][in], 0, 0, 0);
        }
    }
    __syncthreads();
  }

  // Epilogue: C/D layout col = lane&15, row = (lane>>4)*4 + reg
  const int crow = kg * 4;
  #pragma unroll
  for (int im = 0; im < 2; ++im)
    #pragma unroll
    for (int in = 0; in < 2; ++in) {
      const int n = n0 + wn * 32 + in * 16 + fr;
      const int p = n >> 7, c = n & 127;           // p uniform per block
      #pragma unroll
      for (int r = 0; r < 4; ++r) {
        const int m = r0 + wm * 32 + im * 16 + crow + r;
        const float val = acc[im][in][r];
        if (p == 2) {
          vtmp[(size_t)m * DK + c] = val;
        } else {
          const unsigned short h = f2bf(val);
          const unsigned short lo2 = f2bf(val - bf2f(h));
          unsigned short* hd = p ? kh : qh;
          unsigned short* ld = p ? kl : ql;
          hd[(size_t)m * DK + c] = h;
          ld[(size_t)m * DK + c] = lo2;
        }
      }
    }
}

// ---------------------------------------------------------------------------
// Prep 3: transpose v fp32 [B][S][128] -> vT hi/lo bf16 [B][128][S]
// ---------------------------------------------------------------------------
__global__ __launch_bounds__(256) void cvtv_kernel(
    const float* __restrict__ v, unsigned short* __restrict__ vTh,
    unsigned short* __restrict__ vTl)
{
  const int s0 = blockIdx.x * 64, d0 = blockIdx.y * 64, b = blockIdx.z;
  __shared__ float Ts[64][65];
  const int t = threadIdx.x;
  const int r = t >> 4, c4 = (t & 15) * 4;
  #pragma unroll
  for (int rr = 0; rr < 4; ++rr) {
    const int sl = r + 16 * rr;
    *(float4*)&Ts[sl][c4] =
        *(const float4*)&v[((size_t)b * S + s0 + sl) * DK + d0 + c4];
  }
  __syncthreads();
  const int dl = t >> 2, sq = (t & 3) * 16;
  unsigned short hbuf[16], lbuf[16];
  #pragma unroll
  for (int j = 0; j < 16; ++j) {
    const float val = Ts[sq + j][dl];
    hbuf[j] = f2bf(val);
    lbuf[j] = f2bf(val - bf2f(hbuf[j]));
  }
  const size_t o = (size_t)b * DK * S + (size_t)(d0 + dl) * S + s0 + sq;
  #pragma unroll
  for (int half = 0; half < 2; ++half) {
    *(u16x8*)&vTh[o + half * 8] = *(u16x8*)&hbuf[half * 8];
    *(u16x8*)&vTl[o + half * 8] = *(u16x8*)&lbuf[half * 8];
  }
}

// ---------------------------------------------------------------------------
// Kernel B: column-softmax STATS ONLY. grid (NSP, 32, B); block (sp, qt)
// loops st = sp, sp+NSP, ... <= qt. Q staged once, K per iteration.
// ---------------------------------------------------------------------------
__global__ __launch_bounds__(256) void stats_mfma(
    const unsigned short* __restrict__ qh, const unsigned short* __restrict__ ql,
    const unsigned short* __restrict__ kh, const unsigned short* __restrict__ kl,
    float* __restrict__ pm, float* __restrict__ ps)
{
  const int sp = blockIdx.x, qt = blockIdx.y, b = blockIdx.z;
  if (sp > qt) return;
  const int q0 = qt * 64;

  __shared__ unsigned short Bsh[64 * 128], Bsl[64 * 128];   // Q stage / K
  __shared__ float SmL[64 * 2], SeL[64 * 2];

  const int t = threadIdx.x;
  const int l = t & 63, w = t >> 6;
  const int wm = w >> 1, wn = w & 1;
  const int fr = l & 15, kg = l >> 4;

  // ---- stage Q once, pull fragments to registers ----
  #pragma unroll
  for (int i = 0; i < 4; ++i) {
    const int flat = t + i * 256;
    const int row = flat >> 4, sg = flat & 15;
    const int sgs = sg ^ (row & 7);
    const size_t gq = (size_t)(b * S + q0 + row) * DK + sgs * 8;
    gload16(qh + gq, &Bsh[flat * 8]);
    gload16(ql + gq, &Bsl[flat * 8]);
  }
  __syncthreads();
  bf16x8 qfh[2][4], qfl[2][4];
  #pragma unroll
  for (int im = 0; im < 2; ++im)
    #pragma unroll
    for (int ks = 0; ks < 4; ++ks) {
      const int row = wm * 32 + im * 16 + fr;
      const int off = row * 128 + ((ks * 4 + kg) ^ (row & 7)) * 8;
      qfh[im][ks] = *(const bf16x8*)&Bsh[off];
      qfl[im][ks] = *(const bf16x8*)&Bsl[off];
    }
  __syncthreads();   // Q reads done before K overwrites

  for (int st = sp; st <= qt; st += NSP) {
    const int s0 = st * 64;

    // ---- stage K ----
    #pragma unroll
    for (int i = 0; i < 4; ++i) {
      const int flat = t + i * 256;
      const int row = flat >> 4, sg = flat & 15;
      const int sgs = sg ^ (row & 7);
      const size_t gk = (size_t)(b * S + s0 + row) * DK + sgs * 8;
      gload16(kh + gk, &Bsh[flat * 8]);
      gload16(kl + gk, &Bsl[flat * 8]);
    }
    __syncthreads();

    // ---- scores (order must match fused_pv exactly) ----
    f32x4 acc[2][2] = {};
    #pragma unroll
    for (int ks = 0; ks < 4; ++ks) {
      bf16x8 bh[2], bl[2];
      #pragma unroll
      for (int in = 0; in < 2; ++in) {
        const int row = wn * 32 + in * 16 + fr;
        const int off = row * 128 + ((ks * 4 + kg) ^ (row & 7)) * 8;
        bh[in] = *(const bf16x8*)&Bsh[off];
        bl[in] = *(const bf16x8*)&Bsl[off];
      }
      #pragma unroll
      for (int im = 0; im < 2; ++im)
        #pragma unroll
        for (int in = 0; in < 2; ++in) {
          acc[im][in] = __builtin_amdgcn_mfma_f32_16x16x32_bf16(qfh[im][ks], bh[in], acc[im][in], 0, 0, 0);
          acc[im][in] = __builtin_amdgcn_mfma_f32_16x16x32_bf16(qfh[im][ks], bl[in], acc[im][in], 0, 0, 0);
          acc[im][in] = __builtin_amdgcn_mfma_f32_16x16x32_bf16(qfl[im][ks], bh[in], acc[im][in], 0, 0, 0);
        }
    }

    // ---- column stats (softmax over q within this 64-row chunk) ----
    const bool diag = (st == qt);
    float Sm_[2], Se_[2];
    #pragma unroll
    for (int in = 0; in < 2; ++in) {
      const int scol = s0 + wn * 32 + in * 16 + fr;
      float m8 = -INFINITY;
      #pragma unroll
      for (int im = 0; im < 2; ++im)
        #pragma unroll
        for (int r = 0; r < 4; ++r) {
          const int q = q0 + wm * 32 + im * 16 + kg * 4 + r;
          if (!diag || q >= scol) m8 = fmaxf(m8, acc[im][in][r] * SCALE);
        }
      float e8 = 0.f;
      if (m8 > -INFINITY) {
        #pragma unroll
        for (int im = 0; im < 2; ++im)
          #pragma unroll
          for (int r = 0; r < 4; ++r) {
            const int q = q0 + wm * 32 + im * 16 + kg * 4 + r;
            if (!diag || q >= scol) e8 += __expf(acc[im][in][r] * SCALE - m8);
          }
      }
      #pragma unroll
      for (int off = 16; off <= 32; off <<= 1) {
        const float om = __shfl_xor(m8, off);
        const float oe = __shfl_xor(e8, off);
        const float nm = fmaxf(m8, om);
        float ne = 0.f;
        if (m8 > -INFINITY) ne += e8 * __expf(m8 - nm);
        if (om > -INFINITY) ne += oe * __expf(om - nm);
        m8 = nm; e8 = ne;
      }
      Sm_[in] = m8; Se_[in] = e8;
    }
    if (l < 16) {
      #pragma unroll
      for (int in = 0; in < 2; ++in) {
        const int col = wn * 32 + in * 16 + l;
        SmL[col * 2 + wm] = Sm_[in];
        SeL[col * 2 + wm] = Se_[in];
      }
    }
    __syncthreads();
    if (t < 64) {
      const float m0 = SmL[t * 2 + 0], m1 = SmL[t * 2 + 1];
      const float nm = fmaxf(m0, m1);
      float ne = 0.f;
      if (m0 > -INFINITY) ne += SeL[t * 2 + 0] * __expf(m0 - nm);
      if (m1 > -INFINITY) ne += SeL[t * 2 + 1] * __expf(m1 - nm);
      const size_t o = ((size_t)(b * 32 + qt)) * S + s0 + t;
      pm[o] = nm;
      ps[o] = ne;
    }
    __syncthreads();   // Bsh/SmL reads done before next iteration overwrites
  }
}

// ---------------------------------------------------------------------------
// Kernel C: combine 32 row-chunk partials -> per-column max m and 1/sum.
// ---------------------------------------------------------------------------
__global__ void colcombine_kernel(const float* __restrict__ pm, const float* __restrict__ ps,
                                  float* __restrict__ cm, float* __restrict__ cinv)
{
  const int s = blockIdx.x * 256 + threadIdx.x;
  const int b = blockIdx.y;
  const int ch0 = s >> 6;
  float m = -INFINITY;
  for (int ch = ch0; ch < 32; ++ch)
    m = fmaxf(m, pm[((size_t)(b * 32 + ch)) * S + s]);
  float sum = 0.f;
  for (int ch = ch0; ch < 32; ++ch) {
    const size_t i = ((size_t)(b * 32 + ch)) * S + s;
    sum += ps[i] * __expf(pm[i] - m);
  }
  cm[(size_t)b * S + s]   = m;
  cinv[(size_t)b * S + s] = 1.f / sum;   // sum >= 1 (diagonal element)
}

// ---------------------------------------------------------------------------
// zero out (out is atomically accumulated)
// ---------------------------------------------------------------------------
__global__ void zero_out_kernel(float* __restrict__ out)
{
  const size_t idx = (size_t)blockIdx.x * 256 + threadIdx.x;
  ((float4*)out)[idx] = float4{0.f, 0.f, 0.f, 0.f};
}

// ---------------------------------------------------------------------------
// Kernel D: fused second pass. grid (NSP, 32, B); block (sp, qt) loops
// st = sp, sp+NSP, ... <= qt, accumulating PV in registers; ONE atomic
// epilogue per block (atomics 17M -> 7.5M, contention <= NSP-way).
// Per tile: recompute scores (bitwise-identical to stats_mfma), normalize
// in-register, att written nontemporal (write-once data; keeps q/k/vT in L2),
// P plain bf16 in LDS, PV = P x (Vh+Vl). Off-diagonal tiles zero their
// mirror (strict-upper) att tile. LDS 40 KB.
// ---------------------------------------------------------------------------
__global__ __launch_bounds__(256) void fused_pv(
    const unsigned short* __restrict__ qh, const unsigned short* __restrict__ ql,
    const unsigned short* __restrict__ kh, const unsigned short* __restrict__ kl,
    const unsigned short* __restrict__ vTh, const unsigned short* __restrict__ vTl,
    const float* __restrict__ cm, const float* __restrict__ cinv,
    float* __restrict__ att, float* __restrict__ out)
{
  const int sp = blockIdx.x, qt = blockIdx.y, b = blockIdx.z;
  if (sp > qt) return;
  const int q0 = qt * 64;
  float* attb = att + (size_t)b * S * S;
  const unsigned short* vth = vTh + (size_t)b * DK * S;
  const unsigned short* vtl = vTl + (size_t)b * DK * S;

  __shared__ unsigned short Bsh[64 * 128], Bsl[64 * 128];   // Q stage / K / vT
  __shared__ unsigned short Psh[64 * 64];                   // P tile (plain bf16)

  const int t = threadIdx.x;
  const int l = t & 63, w = t >> 6;
  const int wm = w >> 1, wn = w & 1;          // 2x2 wave grid (scores)
  const int fr = l & 15, kg = l >> 4;

  // ---- stage Q tile once, pull fragments to registers ----
  #pragma unroll
  for (int i = 0; i < 4; ++i) {
    const int flat = t + i * 256;
    const int row = flat >> 4, sg = flat & 15;
    const int sgs = sg ^ (row & 7);
    const size_t gq = (size_t)(b * S + q0 + row) * DK + sgs * 8;
    gload16(qh + gq, &Bsh[flat * 8]);
    gload16(ql + gq, &Bsl[flat * 8]);
  }
  __syncthreads();
  bf16x8 qfh[2][4], qfl[2][4];
  #pragma unroll
  for (int im = 0; im < 2; ++im)
    #pragma unroll
    for (int ks = 0; ks < 4; ++ks) {
      const int row = wm * 32 + im * 16 + fr;
      const int off = row * 128 + ((ks * 4 + kg) ^ (row & 7)) * 8;
      qfh[im][ks] = *(const bf16x8*)&Bsh[off];
      qfl[im][ks] = *(const bf16x8*)&Bsl[off];
    }
  __syncthreads();   // all Q reads done before K overwrites

  f32x4 acc[8] = {};   // PV accumulator, persists across st tiles

  for (int st = sp; st <= qt; st += NSP) {
    const int s0 = st * 64;

    // ---- stage K tile ----
    #pragma unroll
    for (int i = 0; i < 4; ++i) {
      const int flat = t + i * 256;
      const int row = flat >> 4, sg = flat & 15;
      const int sgs = sg ^ (row & 7);
      const size_t gk = (size_t)(b * S + s0 + row) * DK + sgs * 8;
      gload16(kh + gk, &Bsh[flat * 8]);
      gload16(kl + gk, &Bsl[flat * 8]);
    }
    __syncthreads();

    // ---- scores: identical accumulation order to stats_mfma ----
    f32x4 sacc[2][2] = {};
    #pragma unroll
    for (int ks = 0; ks < 4; ++ks) {
      bf16x8 bh[2], bl[2];
      #pragma unroll
      for (int in = 0; in < 2; ++in) {
        const int row = wn * 32 + in * 16 + fr;
        const int off = row * 128 + ((ks * 4 + kg) ^ (row & 7)) * 8;
        bh[in] = *(const bf16x8*)&Bsh[off];
        bl[in] = *(const bf16x8*)&Bsl[off];
      }
      #pragma unroll
      for (int im = 0; im < 2; ++im)
        #pragma unroll
        for (int in = 0; in < 2; ++in) {
          sacc[im][in] = __builtin_amdgcn_mfma_f32_16x16x32_bf16(qfh[im][ks], bh[in], sacc[im][in], 0, 0, 0);
          sacc[im][in] = __builtin_amdgcn_mfma_f32_16x16x32_bf16(qfh[im][ks], bl[in], sacc[im][in], 0, 0, 0);
          sacc[im][in] = __builtin_amdgcn_mfma_f32_16x16x32_bf16(qfl[im][ks], bh[in], sacc[im][in], 0, 0, 0);
        }
    }

    // ---- normalize in-register; P (plain bf16) -> LDS; keep x in regs ----
    const bool diag = (st == qt);
    float xv[2][2][4];
    #pragma unroll
    for (int in = 0; in < 2; ++in) {
      const int sloc = wn * 32 + in * 16 + fr;
      const int scol = s0 + sloc;
      const float m   = cm[(size_t)b * S + scol];
      const float inv = cinv[(size_t)b * S + scol];
      #pragma unroll
      for (int im = 0; im < 2; ++im) {
        #pragma unroll
        for (int r = 0; r < 4; ++r) {
          const int qloc = wm * 32 + im * 16 + kg * 4 + r;
          const bool live = !diag || (q0 + qloc >= scol);
          const float x = live ? __expf(sacc[im][in][r] * SCALE - m) * inv : 0.f;
          xv[im][in][r] = x;
          const int idx = qloc * 64 + (((sloc >> 3) ^ (qloc & 7)) * 8 + (sloc & 7));
          Psh[idx] = f2bf(x);
        }
      }
    }
    __syncthreads();   // K reads done + P complete

    // ---- stage vT tile (latency hidden under stores below) ----
    #pragma unroll
    for (int i = 0; i < 4; ++i) {
      const int flat = t + i * 256;
      const int row = flat >> 3, sg = flat & 7;
      const int sgs = sg ^ (row & 7);
      const size_t gv = (size_t)row * S + s0 + sgs * 8;
      gload16(vth + gv, &Bsh[flat * 8]);
      gload16(vtl + gv, &Bsl[flat * 8]);
    }

    // mirror (strict-upper) tile zeroing: rows s0.., cols q0.. (nontemporal)
    if (st < qt) {
      const f32x4 z = {0.f, 0.f, 0.f, 0.f};
      #pragma unroll
      for (int i = 0; i < 4; ++i) {
        const int flat = t + i * 256;          // 0..1023
        const int row = flat >> 4, c4 = (flat & 15) * 4;
        __builtin_nontemporal_store(z, (f32x4*)&attb[(size_t)(s0 + row) * S + q0 + c4]);
      }
    }

    // att writes from registers (fp32, nontemporal — never re-read)
    #pragma unroll
    for (int im = 0; im < 2; ++im)
      #pragma unroll
      for (int in = 0; in < 2; ++in) {
        const int sloc = wn * 32 + in * 16 + fr;
        #pragma unroll
        for (int r = 0; r < 4; ++r) {
          const int qloc = wm * 32 + im * 16 + kg * 4 + r;
          __builtin_nontemporal_store(xv[im][in][r],
                                      &attb[(size_t)(q0 + qloc) * S + s0 + sloc]);
        }
      }
    __syncthreads();   // V ready

    // ---- PV: wave w computes q rows [w*16, w*16+16), all 128 d cols ----
    #pragma unroll
    for (int ks2 = 0; ks2 < 2; ++ks2) {
      const int arow = w * 16 + fr;
      const int aoff = arow * 64 + ((ks2 * 4 + kg) ^ (arow & 7)) * 8;
      const bf16x8 a = *(const bf16x8*)&Psh[aoff];
      #pragma unroll
      for (int in = 0; in < 8; ++in) {
        const int brow = in * 16 + fr;
        const int boff = brow * 64 + ((ks2 * 4 + kg) ^ (brow & 7)) * 8;
        const bf16x8 b_h = *(const bf16x8*)&Bsh[boff];
        const bf16x8 b_l = *(const bf16x8*)&Bsl[boff];
        acc[in] = __builtin_amdgcn_mfma_f32_16x16x32_bf16(a, b_h, acc[in], 0, 0, 0);
        acc[in] = __builtin_amdgcn_mfma_f32_16x16x32_bf16(a, b_l, acc[in], 0, 0, 0);
      }
    }
    __syncthreads();   // PV's Bsh/Psh reads done before next K overwrite
  }

  // ---- single atomic epilogue per block ----
  #pragma unroll
  for (int in = 0; in < 8; ++in) {
    #pragma unroll
    for (int r = 0; r < 4; ++r) {
      const int q = q0 + w * 16 + kg * 4 + r;
      const int d = in * 16 + fr;
      atomicAdd(&out[((size_t)b * S + q) * DK + d], acc[in][r]);
    }
  }
}

// ---------------------------------------------------------------------------
extern "C" void kernel_launch(void* const* d_in, const int* in_sizes, int n_in,
                              void* d_out, int out_size, void* d_ws, size_t ws_size,
                              hipStream_t stream)
{
  const float* vin = (const float*)d_in[0];
  const float* wq  = (const float*)d_in[1];
  const float* wk  = (const float*)d_in[2];
  const float* wv  = (const float*)d_in[3];

  float* out = (float*)d_out;
  float* att = out + (size_t)B * S * DK;     // attention output region (64 MB)

  // bf16 copies of vin / W live INSIDE the att region (dead before att writes)
  unsigned short* Ah  = (unsigned short*)att;
  unsigned short* Al  = Ah  + (size_t)BS * DM;
  unsigned short* Wth = Al  + (size_t)BS * DM;
  unsigned short* Wtl = Wth + (size_t)384 * DM;

  constexpr size_t NE = (size_t)BS * DK;     // 1048576
  unsigned short* qh  = (unsigned short*)d_ws;
  unsigned short* ql  = qh  + NE;
  unsigned short* kh  = ql  + NE;
  unsigned short* kl  = kh  + NE;
  unsigned short* vTh = kl  + NE;
  unsigned short* vTl = vTh + NE;
  float* vtmp = (float*)(vTl + NE);          // 4 MB
  float* pm   = vtmp;                        // aliases vtmp (v dead by then)
  float* ps   = pm + 32ull * B * S;          // 1 MB each
  float* cm   = ps + 32ull * B * S;
  float* cinv = cm + (size_t)B * S;

  cvt_hilo         <<<dim3(BS * DM / 1024),  256, 0, stream>>>(vin, Ah, Al);
  cvtw_kernel      <<<dim3(384),             256, 0, stream>>>(wq, wk, wv, Wth, Wtl);
  proj_mfma        <<<dim3(128, 6),          256, 0, stream>>>(Ah, Al, Wth, Wtl,
                                                               qh, ql, kh, kl, vtmp);
  cvtv_kernel      <<<dim3(S / 64, 2, B),    256, 0, stream>>>(vtmp, vTh, vTl);
  zero_out_kernel  <<<dim3(BS * DK / 1024),  256, 0, stream>>>(out);
  stats_mfma       <<<dim3(NSP, 32, B),      256, 0, stream>>>(qh, ql, kh, kl, pm, ps);
  colcombine_kernel<<<dim3(S / 256, B),      256, 0, stream>>>(pm, ps, cm, cinv);
  fused_pv         <<<dim3(NSP, 32, B),      256, 0, stream>>>(qh, ql, kh, kl, vTh, vTl,
                                                               cm, cinv, att, out);
}

// Round 12
// 117.815 us; speedup vs baseline: 1.2690x; 1.0004x over previous
//
#include <hip/hip_runtime.h>
#include <math.h>

// Problem constants
constexpr int B  = 4;
constexpr int S  = 2048;
constexpr int DM = 1024;
constexpr int DK = 128;
constexpr int BS = B * S;
constexpr int NSP = 8;      // st-split factor (contention <= 8-way)

static constexpr float SCALE = 0.08838834764831845f; // 1/sqrt(128)

typedef __attribute__((ext_vector_type(8))) short bf16x8;
typedef __attribute__((ext_vector_type(4))) float f32x4;
typedef __attribute__((ext_vector_type(8))) unsigned short u16x8;

__device__ __forceinline__ unsigned short f2bf(float x) {
  unsigned u = __float_as_uint(x);
  unsigned r = (u + 0x7FFFu + ((u >> 16) & 1u)) >> 16;   // RNE
  return (unsigned short)r;
}
__device__ __forceinline__ float bf2f(unsigned short h) {
  return __uint_as_float(((unsigned)h) << 16);
}

__device__ __forceinline__ void gload16(const void* g, void* l) {
  __builtin_amdgcn_global_load_lds(
      (const __attribute__((address_space(1))) void*)g,
      (__attribute__((address_space(3))) void*)l, 16, 0, 0);
}

// ---------------------------------------------------------------------------
// Prep 1: vin fp32 -> Ah (bf16 RNE) + Al (bf16 of residual), row-major [BS][DM]
// ---------------------------------------------------------------------------
__global__ __launch_bounds__(256) void cvt_hilo(
    const float* __restrict__ x, unsigned short* __restrict__ hi,
    unsigned short* __restrict__ lo)
{
  const size_t idx = (size_t)blockIdx.x * 256 + threadIdx.x;  // float4 index
  const float4 v = ((const float4*)x)[idx];
  ushort4 h, l;
  h.x = f2bf(v.x); l.x = f2bf(v.x - bf2f(h.x));
  h.y = f2bf(v.y); l.y = f2bf(v.y - bf2f(h.y));
  h.z = f2bf(v.z); l.z = f2bf(v.z - bf2f(h.z));
  h.w = f2bf(v.w); l.w = f2bf(v.w - bf2f(h.w));
  ((ushort4*)hi)[idx] = h;
  ((ushort4*)lo)[idx] = l;
}

// ---------------------------------------------------------------------------
// Prep 2: w_q/w_k/w_v [1024][128] fp32 -> Wt hi/lo bf16 [384][1024] (B^T)
// ---------------------------------------------------------------------------
__global__ void cvtw_kernel(const float* __restrict__ wq, const float* __restrict__ wk,
                            const float* __restrict__ wv,
                            unsigned short* __restrict__ Wth, unsigned short* __restrict__ Wtl)
{
  const int n = blockIdx.x;            // 0..383
  const int p = n >> 7, c = n & 127;
  const float* w = (p == 0) ? wq : (p == 1) ? wk : wv;
  for (int k = threadIdx.x; k < DM; k += 256) {
    const float x = w[(size_t)k * DK + c];
    const unsigned short h = f2bf(x);
    Wth[(size_t)n * DM + k] = h;
    Wtl[(size_t)n * DM + k] = f2bf(x - bf2f(h));
  }
}

// ---------------------------------------------------------------------------
// Kernel A: projections via split-bf16 MFMA. Emits q,k as bf16 hi/lo pairs
// [BS][128] and v as fp32 [BS][128]. XOR-swizzled LDS (T2, src-side).
// ---------------------------------------------------------------------------
__global__ __launch_bounds__(256) void proj_mfma(
    const unsigned short* __restrict__ Ah, const unsigned short* __restrict__ Al,
    const unsigned short* __restrict__ Wh, const unsigned short* __restrict__ Wl,
    unsigned short* __restrict__ qh, unsigned short* __restrict__ ql,
    unsigned short* __restrict__ kh, unsigned short* __restrict__ kl,
    float* __restrict__ vtmp)
{
  __shared__ unsigned short Ash[2][64 * 64];
  __shared__ unsigned short Wsh[2][64 * 64];

  const int r0 = blockIdx.x * 64;      // M tile
  const int n0 = blockIdx.y * 64;      // N tile (384/64 = 6)
  const int t  = threadIdx.x;
  const int l  = t & 63, w = t >> 6;
  const int wm = w >> 1, wn = w & 1;   // 2x2 wave grid
  const int fr = l & 15, kg = l >> 4;  // fragment row / k-group

  f32x4 acc[2][2] = {};

  for (int k0 = 0; k0 < DM; k0 += 64) {
    #pragma unroll
    for (int i = 0; i < 2; ++i) {
      const int flat = t + i * 256;          // 512 16B segments per tile
      const int row = flat >> 3, sg = flat & 7;
      const int sgs = sg ^ (row & 7);        // pre-swizzled source (T2)
      const size_t ga = (size_t)(r0 + row) * DM + k0 + sgs * 8;
      const size_t gw = (size_t)(n0 + row) * DM + k0 + sgs * 8;
      gload16(Ah + ga, &Ash[0][flat * 8]);
      gload16(Al + ga, &Ash[1][flat * 8]);
      gload16(Wh + gw, &Wsh[0][flat * 8]);
      gload16(Wl + gw, &Wsh[1][flat * 8]);
    }
    __syncthreads();

    #pragma unroll
    for (int kk = 0; kk < 2; ++kk) {
      bf16x8 ah[2], al[2], bh[2], bl[2];
      #pragma unroll
      for (int im = 0; im < 2; ++im) {
        const int row = wm * 32 + im * 16 + fr;
        const int off = row * 64 + ((kk * 4 + kg) ^ (row & 7)) * 8;
        ah[im] = *(const bf16x8*)&Ash[0][off];
        al[im] = *(const bf16x8*)&Ash[1][off];
      }
      #pragma unroll
      for (int in = 0; in < 2; ++in) {
        const int row = wn * 32 + in * 16 + fr;
        const int off = row * 64 + ((kk * 4 + kg) ^ (row & 7)) * 8;
        bh[in] = *(const bf16x8*)&Wsh[0][off];
        bl[in] = *(const bf16x8*)&Wsh[1][off];
      }
      #pragma unroll
      for (int im = 0; im < 2; ++im)
        #pragma unroll
        for (int in = 0; in < 2; ++in) {
          acc[im][in] = __builtin_amdgcn_mfma_f32_16x16x32_bf16(ah[im], bh[in], acc[im][in], 0, 0, 0);
          acc[im][in] = __builtin_amdgcn_mfma_f32_16x16x32_bf16(ah[im], bl[in], acc[im][in], 0, 0, 0);
          acc[im][in] = __builtin_amdgcn_mfma_f32_16x16x32_bf16(al[im], bh[in], acc[im][in], 0, 0, 0);
        }
    }
    __syncthreads();
  }

  // Epilogue: C/D layout col = lane&15, row = (lane>>4)*4 + reg
  const int crow = kg * 4;
  #pragma unroll
  for (int im = 0; im < 2; ++im)
    #pragma unroll
    for (int in = 0; in < 2; ++in) {
      const int n = n0 + wn * 32 + in * 16 + fr;
      const int p = n >> 7, c = n & 127;           // p uniform per block
      #pragma unroll
      for (int r = 0; r < 4; ++r) {
        const int m = r0 + wm * 32 + im * 16 + crow + r;
        const float val = acc[im][in][r];
        if (p == 2) {
          vtmp[(size_t)m * DK + c] = val;
        } else {
          const unsigned short h = f2bf(val);
          const unsigned short lo2 = f2bf(val - bf2f(h));
          unsigned short* hd = p ? kh : qh;
          unsigned short* ld = p ? kl : ql;
          hd[(size_t)m * DK + c] = h;
          ld[(size_t)m * DK + c] = lo2;
        }
      }
    }
}

// ---------------------------------------------------------------------------
// Prep 3: transpose v fp32 [B][S][128] -> vT hi/lo bf16 [B][128][S]
// ---------------------------------------------------------------------------
__global__ __launch_bounds__(256) void cvtv_kernel(
    const float* __restrict__ v, unsigned short* __restrict__ vTh,
    unsigned short* __restrict__ vTl)
{
  const int s0 = blockIdx.x * 64, d0 = blockIdx.y * 64, b = blockIdx.z;
  __shared__ float Ts[64][65];
  const int t = threadIdx.x;
  const int r = t >> 4, c4 = (t & 15) * 4;
  #pragma unroll
  for (int rr = 0; rr < 4; ++rr) {
    const int sl = r + 16 * rr;
    *(float4*)&Ts[sl][c4] =
        *(const float4*)&v[((size_t)b * S + s0 + sl) * DK + d0 + c4];
  }
  __syncthreads();
  const int dl = t >> 2, sq = (t & 3) * 16;
  unsigned short hbuf[16], lbuf[16];
  #pragma unroll
  for (int j = 0; j < 16; ++j) {
    const float val = Ts[sq + j][dl];
    hbuf[j] = f2bf(val);
    lbuf[j] = f2bf(val - bf2f(hbuf[j]));
  }
  const size_t o = (size_t)b * DK * S + (size_t)(d0 + dl) * S + s0 + sq;
  #pragma unroll
  for (int half = 0; half < 2; ++half) {
    *(u16x8*)&vTh[o + half * 8] = *(u16x8*)&hbuf[half * 8];
    *(u16x8*)&vTl[o + half * 8] = *(u16x8*)&lbuf[half * 8];
  }
}

// ---------------------------------------------------------------------------
// Kernel B: column-softmax STATS ONLY. grid (NSP, 32, B); block (sp, qt)
// loops st = sp, sp+NSP, ... <= qt. Q staged once, K per iteration.
// ---------------------------------------------------------------------------
__global__ __launch_bounds__(256) void stats_mfma(
    const unsigned short* __restrict__ qh, const unsigned short* __restrict__ ql,
    const unsigned short* __restrict__ kh, const unsigned short* __restrict__ kl,
    float* __restrict__ pm, float* __restrict__ ps)
{
  const int sp = blockIdx.x, qt = blockIdx.y, b = blockIdx.z;
  if (sp > qt) return;
  const int q0 = qt * 64;

  __shared__ unsigned short Bsh[64 * 128], Bsl[64 * 128];   // Q stage / K
  __shared__ float SmL[64 * 2], SeL[64 * 2];

  const int t = threadIdx.x;
  const int l = t & 63, w = t >> 6;
  const int wm = w >> 1, wn = w & 1;
  const int fr = l & 15, kg = l >> 4;

  // ---- stage Q once, pull fragments to registers ----
  #pragma unroll
  for (int i = 0; i < 4; ++i) {
    const int flat = t + i * 256;
    const int row = flat >> 4, sg = flat & 15;
    const int sgs = sg ^ (row & 7);
    const size_t gq = (size_t)(b * S + q0 + row) * DK + sgs * 8;
    gload16(qh + gq, &Bsh[flat * 8]);
    gload16(ql + gq, &Bsl[flat * 8]);
  }
  __syncthreads();
  bf16x8 qfh[2][4], qfl[2][4];
  #pragma unroll
  for (int im = 0; im < 2; ++im)
    #pragma unroll
    for (int ks = 0; ks < 4; ++ks) {
      const int row = wm * 32 + im * 16 + fr;
      const int off = row * 128 + ((ks * 4 + kg) ^ (row & 7)) * 8;
      qfh[im][ks] = *(const bf16x8*)&Bsh[off];
      qfl[im][ks] = *(const bf16x8*)&Bsl[off];
    }
  __syncthreads();   // Q reads done before K overwrites

  for (int st = sp; st <= qt; st += NSP) {
    const int s0 = st * 64;

    // ---- stage K ----
    #pragma unroll
    for (int i = 0; i < 4; ++i) {
      const int flat = t + i * 256;
      const int row = flat >> 4, sg = flat & 15;
      const int sgs = sg ^ (row & 7);
      const size_t gk = (size_t)(b * S + s0 + row) * DK + sgs * 8;
      gload16(kh + gk, &Bsh[flat * 8]);
      gload16(kl + gk, &Bsl[flat * 8]);
    }
    __syncthreads();

    // ---- scores (order must match fused_pv exactly) ----
    f32x4 acc[2][2] = {};
    #pragma unroll
    for (int ks = 0; ks < 4; ++ks) {
      bf16x8 bh[2], bl[2];
      #pragma unroll
      for (int in = 0; in < 2; ++in) {
        const int row = wn * 32 + in * 16 + fr;
        const int off = row * 128 + ((ks * 4 + kg) ^ (row & 7)) * 8;
        bh[in] = *(const bf16x8*)&Bsh[off];
        bl[in] = *(const bf16x8*)&Bsl[off];
      }
      #pragma unroll
      for (int im = 0; im < 2; ++im)
        #pragma unroll
        for (int in = 0; in < 2; ++in) {
          acc[im][in] = __builtin_amdgcn_mfma_f32_16x16x32_bf16(qfh[im][ks], bh[in], acc[im][in], 0, 0, 0);
          acc[im][in] = __builtin_amdgcn_mfma_f32_16x16x32_bf16(qfh[im][ks], bl[in], acc[im][in], 0, 0, 0);
          acc[im][in] = __builtin_amdgcn_mfma_f32_16x16x32_bf16(qfl[im][ks], bh[in], acc[im][in], 0, 0, 0);
        }
    }

    // ---- column stats (softmax over q within this 64-row chunk) ----
    const bool diag = (st == qt);
    float Sm_[2], Se_[2];
    #pragma unroll
    for (int in = 0; in < 2; ++in) {
      const int scol = s0 + wn * 32 + in * 16 + fr;
      float m8 = -INFINITY;
      #pragma unroll
      for (int im = 0; im < 2; ++im)
        #pragma unroll
        for (int r = 0; r < 4; ++r) {
          const int q = q0 + wm * 32 + im * 16 + kg * 4 + r;
          if (!diag || q >= scol) m8 = fmaxf(m8, acc[im][in][r] * SCALE);
        }
      float e8 = 0.f;
      if (m8 > -INFINITY) {
        #pragma unroll
        for (int im = 0; im < 2; ++im)
          #pragma unroll
          for (int r = 0; r < 4; ++r) {
            const int q = q0 + wm * 32 + im * 16 + kg * 4 + r;
            if (!diag || q >= scol) e8 += __expf(acc[im][in][r] * SCALE - m8);
          }
      }
      #pragma unroll
      for (int off = 16; off <= 32; off <<= 1) {
        const float om = __shfl_xor(m8, off);
        const float oe = __shfl_xor(e8, off);
        const float nm = fmaxf(m8, om);
        float ne = 0.f;
        if (m8 > -INFINITY) ne += e8 * __expf(m8 - nm);
        if (om > -INFINITY) ne += oe * __expf(om - nm);
        m8 = nm; e8 = ne;
      }
      Sm_[in] = m8; Se_[in] = e8;
    }
    if (l < 16) {
      #pragma unroll
      for (int in = 0; in < 2; ++in) {
        const int col = wn * 32 + in * 16 + l;
        SmL[col * 2 + wm] = Sm_[in];
        SeL[col * 2 + wm] = Se_[in];
      }
    }
    __syncthreads();
    if (t < 64) {
      const float m0 = SmL[t * 2 + 0], m1 = SmL[t * 2 + 1];
      const float nm = fmaxf(m0, m1);
      float ne = 0.f;
      if (m0 > -INFINITY) ne += SeL[t * 2 + 0] * __expf(m0 - nm);
      if (m1 > -INFINITY) ne += SeL[t * 2 + 1] * __expf(m1 - nm);
      const size_t o = ((size_t)(b * 32 + qt)) * S + s0 + t;
      pm[o] = nm;
      ps[o] = ne;
    }
    __syncthreads();   // Bsh/SmL reads done before next iteration overwrites
  }
}

// ---------------------------------------------------------------------------
// Kernel C: combine 32 row-chunk partials -> per-column max m and 1/sum.
// ---------------------------------------------------------------------------
__global__ void colcombine_kernel(const float* __restrict__ pm, const float* __restrict__ ps,
                                  float* __restrict__ cm, float* __restrict__ cinv)
{
  const int s = blockIdx.x * 256 + threadIdx.x;
  const int b = blockIdx.y;
  const int ch0 = s >> 6;
  float m = -INFINITY;
  for (int ch = ch0; ch < 32; ++ch)
    m = fmaxf(m, pm[((size_t)(b * 32 + ch)) * S + s]);
  float sum = 0.f;
  for (int ch = ch0; ch < 32; ++ch) {
    const size_t i = ((size_t)(b * 32 + ch)) * S + s;
    sum += ps[i] * __expf(pm[i] - m);
  }
  cm[(size_t)b * S + s]   = m;
  cinv[(size_t)b * S + s] = 1.f / sum;   // sum >= 1 (diagonal element)
}

// ---------------------------------------------------------------------------
// zero out (out is atomically accumulated)
// ---------------------------------------------------------------------------
__global__ void zero_out_kernel(float* __restrict__ out)
{
  const size_t idx = (size_t)blockIdx.x * 256 + threadIdx.x;
  ((float4*)out)[idx] = float4{0.f, 0.f, 0.f, 0.f};
}

// ---------------------------------------------------------------------------
// Kernel D: fused second pass. grid (NSP, 32, B); block (sp, qt) loops
// st = sp, sp+NSP, ... <= qt, accumulating PV in registers; one atomic
// epilogue per block. Per tile: K and V staged TOGETHER into separate LDS
// buffers (one joint vmcnt drain instead of two sequential — the round-12
// lever), scores recomputed (bitwise-identical to stats_mfma), normalize
// in-register, att written nontemporal, P plain bf16 in LDS, PV = P x (Vh+Vl).
// 3 barriers/tile. LDS 72 KB -> 2 blocks/CU.
// ---------------------------------------------------------------------------
__global__ __launch_bounds__(256) void fused_pv(
    const unsigned short* __restrict__ qh, const unsigned short* __restrict__ ql,
    const unsigned short* __restrict__ kh, const unsigned short* __restrict__ kl,
    const unsigned short* __restrict__ vTh, const unsigned short* __restrict__ vTl,
    const float* __restrict__ cm, const float* __restrict__ cinv,
    float* __restrict__ att, float* __restrict__ out)
{
  const int sp = blockIdx.x, qt = blockIdx.y, b = blockIdx.z;
  if (sp > qt) return;
  const int q0 = qt * 64;
  float* attb = att + (size_t)b * S * S;
  const unsigned short* vth = vTh + (size_t)b * DK * S;
  const unsigned short* vtl = vTl + (size_t)b * DK * S;

  __shared__ unsigned short Ksh[64 * 128], Ksl[64 * 128];   // Q stage / K (32 KB)
  __shared__ unsigned short Vsh[128 * 64], Vsl[128 * 64];   // vT tile (32 KB)
  __shared__ unsigned short Psh[64 * 64];                   // P tile (8 KB)

  const int t = threadIdx.x;
  const int l = t & 63, w = t >> 6;
  const int wm = w >> 1, wn = w & 1;          // 2x2 wave grid (scores)
  const int fr = l & 15, kg = l >> 4;

  // ---- stage Q tile once, pull fragments to registers ----
  #pragma unroll
  for (int i = 0; i < 4; ++i) {
    const int flat = t + i * 256;
    const int row = flat >> 4, sg = flat & 15;
    const int sgs = sg ^ (row & 7);
    const size_t gq = (size_t)(b * S + q0 + row) * DK + sgs * 8;
    gload16(qh + gq, &Ksh[flat * 8]);
    gload16(ql + gq, &Ksl[flat * 8]);
  }
  __syncthreads();
  bf16x8 qfh[2][4], qfl[2][4];
  #pragma unroll
  for (int im = 0; im < 2; ++im)
    #pragma unroll
    for (int ks = 0; ks < 4; ++ks) {
      const int row = wm * 32 + im * 16 + fr;
      const int off = row * 128 + ((ks * 4 + kg) ^ (row & 7)) * 8;
      qfh[im][ks] = *(const bf16x8*)&Ksh[off];
      qfl[im][ks] = *(const bf16x8*)&Ksl[off];
    }
  __syncthreads();   // all Q reads done before K overwrites

  f32x4 acc[8] = {};   // PV accumulator, persists across st tiles

  for (int st = sp; st <= qt; st += NSP) {
    const int s0 = st * 64;

    // ---- stage K AND V tiles together (one joint drain) ----
    #pragma unroll
    for (int i = 0; i < 4; ++i) {
      const int flat = t + i * 256;
      const int row = flat >> 4, sg = flat & 15;
      const int sgs = sg ^ (row & 7);
      const size_t gk = (size_t)(b * S + s0 + row) * DK + sgs * 8;
      gload16(kh + gk, &Ksh[flat * 8]);
      gload16(kl + gk, &Ksl[flat * 8]);
    }
    #pragma unroll
    for (int i = 0; i < 4; ++i) {
      const int flat = t + i * 256;
      const int row = flat >> 3, sg = flat & 7;
      const int sgs = sg ^ (row & 7);
      const size_t gv = (size_t)row * S + s0 + sgs * 8;
      gload16(vth + gv, &Vsh[flat * 8]);
      gload16(vtl + gv, &Vsl[flat * 8]);
    }
    __syncthreads();   // K and V both resident

    // ---- scores: identical accumulation order to stats_mfma ----
    f32x4 sacc[2][2] = {};
    #pragma unroll
    for (int ks = 0; ks < 4; ++ks) {
      bf16x8 bh[2], bl[2];
      #pragma unroll
      for (int in = 0; in < 2; ++in) {
        const int row = wn * 32 + in * 16 + fr;
        const int off = row * 128 + ((ks * 4 + kg) ^ (row & 7)) * 8;
        bh[in] = *(const bf16x8*)&Ksh[off];
        bl[in] = *(const bf16x8*)&Ksl[off];
      }
      #pragma unroll
      for (int im = 0; im < 2; ++im)
        #pragma unroll
        for (int in = 0; in < 2; ++in) {
          sacc[im][in] = __builtin_amdgcn_mfma_f32_16x16x32_bf16(qfh[im][ks], bh[in], sacc[im][in], 0, 0, 0);
          sacc[im][in] = __builtin_amdgcn_mfma_f32_16x16x32_bf16(qfh[im][ks], bl[in], sacc[im][in], 0, 0, 0);
          sacc[im][in] = __builtin_amdgcn_mfma_f32_16x16x32_bf16(qfl[im][ks], bh[in], sacc[im][in], 0, 0, 0);
        }
    }

    // ---- normalize in-register; P (plain bf16) -> LDS; att nontemporal ----
    const bool diag = (st == qt);
    float xv[2][2][4];
    #pragma unroll
    for (int in = 0; in < 2; ++in) {
      const int sloc = wn * 32 + in * 16 + fr;
      const int scol = s0 + sloc;
      const float m   = cm[(size_t)b * S + scol];
      const float inv = cinv[(size_t)b * S + scol];
      #pragma unroll
      for (int im = 0; im < 2; ++im) {
        #pragma unroll
        for (int r = 0; r < 4; ++r) {
          const int qloc = wm * 32 + im * 16 + kg * 4 + r;
          const bool live = !diag || (q0 + qloc >= scol);
          const float x = live ? __expf(sacc[im][in][r] * SCALE - m) * inv : 0.f;
          xv[im][in][r] = x;
          const int idx = qloc * 64 + (((sloc >> 3) ^ (qloc & 7)) * 8 + (sloc & 7));
          Psh[idx] = f2bf(x);
        }
      }
    }

    // mirror (strict-upper) tile zeroing: rows s0.., cols q0.. (nontemporal)
    if (st < qt) {
      const f32x4 z = {0.f, 0.f, 0.f, 0.f};
      #pragma unroll
      for (int i = 0; i < 4; ++i) {
        const int flat = t + i * 256;          // 0..1023
        const int row = flat >> 4, c4 = (flat & 15) * 4;
        __builtin_nontemporal_store(z, (f32x4*)&attb[(size_t)(s0 + row) * S + q0 + c4]);
      }
    }

    // att writes from registers (fp32, nontemporal — never re-read)
    #pragma unroll
    for (int im = 0; im < 2; ++im)
      #pragma unroll
      for (int in = 0; in < 2; ++in) {
        const int sloc = wn * 32 + in * 16 + fr;
        #pragma unroll
        for (int r = 0; r < 4; ++r) {
          const int qloc = wm * 32 + im * 16 + kg * 4 + r;
          __builtin_nontemporal_store(xv[im][in][r],
                                      &attb[(size_t)(q0 + qloc) * S + s0 + sloc]);
        }
      }
    __syncthreads();   // P visible (V already resident)

    // ---- PV: wave w computes q rows [w*16, w*16+16), all 128 d cols ----
    #pragma unroll
    for (int ks2 = 0; ks2 < 2; ++ks2) {
      const int arow = w * 16 + fr;
      const int aoff = arow * 64 + ((ks2 * 4 + kg) ^ (arow & 7)) * 8;
      const bf16x8 a = *(const bf16x8*)&Psh[aoff];
      #pragma unroll
      for (int in = 0; in < 8; ++in) {
        const int brow = in * 16 + fr;
        const int boff = brow * 64 + ((ks2 * 4 + kg) ^ (brow & 7)) * 8;
        const bf16x8 b_h = *(const bf16x8*)&Vsh[boff];
        const bf16x8 b_l = *(const bf16x8*)&Vsl[boff];
        acc[in] = __builtin_amdgcn_mfma_f32_16x16x32_bf16(a, b_h, acc[in], 0, 0, 0);
        acc[in] = __builtin_amdgcn_mfma_f32_16x16x32_bf16(a, b_l, acc[in], 0, 0, 0);
      }
    }
    __syncthreads();   // PV's Vsh/Psh reads done before next stage overwrites
  }

  // ---- single atomic epilogue per block ----
  #pragma unroll
  for (int in = 0; in < 8; ++in) {
    #pragma unroll
    for (int r = 0; r < 4; ++r) {
      const int q = q0 + w * 16 + kg * 4 + r;
      const int d = in * 16 + fr;
      atomicAdd(&out[((size_t)b * S + q) * DK + d], acc[in][r]);
    }
  }
}

// ---------------------------------------------------------------------------
extern "C" void kernel_launch(void* const* d_in, const int* in_sizes, int n_in,
                              void* d_out, int out_size, void* d_ws, size_t ws_size,
                              hipStream_t stream)
{
  const float* vin = (const float*)d_in[0];
  const float* wq  = (const float*)d_in[1];
  const float* wk  = (const float*)d_in[2];
  const float* wv  = (const float*)d_in[3];

  float* out = (float*)d_out;
  float* att = out + (size_t)B * S * DK;     // attention output region (64 MB)

  // bf16 copies of vin / W live INSIDE the att region (dead before att writes)
  unsigned short* Ah  = (unsigned short*)att;
  unsigned short* Al  = Ah  + (size_t)BS * DM;
  unsigned short* Wth = Al  + (size_t)BS * DM;
  unsigned short* Wtl = Wth + (size_t)384 * DM;

  constexpr size_t NE = (size_t)BS * DK;     // 1048576
  unsigned short* qh  = (unsigned short*)d_ws;
  unsigned short* ql  = qh  + NE;
  unsigned short* kh  = ql  + NE;
  unsigned short* kl  = kh  + NE;
  unsigned short* vTh = kl  + NE;
  unsigned short* vTl = vTh + NE;
  float* vtmp = (float*)(vTl + NE);          // 4 MB
  float* pm   = vtmp;                        // aliases vtmp (v dead by then)
  float* ps   = pm + 32ull * B * S;          // 1 MB each
  float* cm   = ps + 32ull * B * S;
  float* cinv = cm + (size_t)B * S;

  cvt_hilo         <<<dim3(BS * DM / 1024),  256, 0, stream>>>(vin, Ah, Al);
  cvtw_kernel      <<<dim3(384),             256, 0, stream>>>(wq, wk, wv, Wth, Wtl);
  proj_mfma        <<<dim3(128, 6),          256, 0, stream>>>(Ah, Al, Wth, Wtl,
                                                               qh, ql, kh, kl, vtmp);
  cvtv_kernel      <<<dim3(S / 64, 2, B),    256, 0, stream>>>(vtmp, vTh, vTl);
  zero_out_kernel  <<<dim3(BS * DK / 1024),  256, 0, stream>>>(out);
  stats_mfma       <<<dim3(NSP, 32, B),      256, 0, stream>>>(qh, ql, kh, kl, pm, ps);
  colcombine_kernel<<<dim3(S / 256, B),      256, 0, stream>>>(pm, ps, cm, cinv);
  fused_pv         <<<dim3(NSP, 32, B),      256, 0, stream>>>(qh, ql, kh, kl, vTh, vTl,
                                                               cm, cinv, att, out);
}

// Round 13
// 115.525 us; speedup vs baseline: 1.2942x; 1.0198x over previous
//
#include <hip/hip_runtime.h>
#include <math.h>

// Problem constants
constexpr int B  = 4;
constexpr int S  = 2048;
constexpr int DM = 1024;
constexpr int DK = 128;
constexpr int BS = B * S;
constexpr int NSP = 8;      // st-split factor (contention <= 8-way)

static constexpr float SCALE = 0.08838834764831845f; // 1/sqrt(128)

typedef __attribute__((ext_vector_type(8))) short bf16x8;
typedef __attribute__((ext_vector_type(4))) float f32x4;
typedef __attribute__((ext_vector_type(8))) unsigned short u16x8;

__device__ __forceinline__ unsigned short f2bf(float x) {
  unsigned u = __float_as_uint(x);
  unsigned r = (u + 0x7FFFu + ((u >> 16) & 1u)) >> 16;   // RNE
  return (unsigned short)r;
}
__device__ __forceinline__ float bf2f(unsigned short h) {
  return __uint_as_float(((unsigned)h) << 16);
}

__device__ __forceinline__ void gload16(const void* g, void* l) {
  __builtin_amdgcn_global_load_lds(
      (const __attribute__((address_space(1))) void*)g,
      (__attribute__((address_space(3))) void*)l, 16, 0, 0);
}

// ---------------------------------------------------------------------------
// Prep 1: vin fp32 -> Ah (bf16 RNE) + Al (bf16 of residual), row-major [BS][DM]
// ---------------------------------------------------------------------------
__global__ __launch_bounds__(256) void cvt_hilo(
    const float* __restrict__ x, unsigned short* __restrict__ hi,
    unsigned short* __restrict__ lo)
{
  const size_t idx = (size_t)blockIdx.x * 256 + threadIdx.x;  // float4 index
  const float4 v = ((const float4*)x)[idx];
  ushort4 h, l;
  h.x = f2bf(v.x); l.x = f2bf(v.x - bf2f(h.x));
  h.y = f2bf(v.y); l.y = f2bf(v.y - bf2f(h.y));
  h.z = f2bf(v.z); l.z = f2bf(v.z - bf2f(h.z));
  h.w = f2bf(v.w); l.w = f2bf(v.w - bf2f(h.w));
  ((ushort4*)hi)[idx] = h;
  ((ushort4*)lo)[idx] = l;
}

// ---------------------------------------------------------------------------
// Prep 2: w_q/w_k/w_v [1024][128] fp32 -> Wt hi/lo bf16 [384][1024] (B^T)
// ---------------------------------------------------------------------------
__global__ void cvtw_kernel(const float* __restrict__ wq, const float* __restrict__ wk,
                            const float* __restrict__ wv,
                            unsigned short* __restrict__ Wth, unsigned short* __restrict__ Wtl)
{
  const int n = blockIdx.x;            // 0..383
  const int p = n >> 7, c = n & 127;
  const float* w = (p == 0) ? wq : (p == 1) ? wk : wv;
  for (int k = threadIdx.x; k < DM; k += 256) {
    const float x = w[(size_t)k * DK + c];
    const unsigned short h = f2bf(x);
    Wth[(size_t)n * DM + k] = h;
    Wtl[(size_t)n * DM + k] = f2bf(x - bf2f(h));
  }
}

// ---------------------------------------------------------------------------
// Kernel A: projections via split-bf16 MFMA. Emits q,k as bf16 hi/lo pairs
// [BS][128] and v as fp32 [BS][128]. XOR-swizzled LDS (T2, src-side).
// ---------------------------------------------------------------------------
__global__ __launch_bounds__(256) void proj_mfma(
    const unsigned short* __restrict__ Ah, const unsigned short* __restrict__ Al,
    const unsigned short* __restrict__ Wh, const unsigned short* __restrict__ Wl,
    unsigned short* __restrict__ qh, unsigned short* __restrict__ ql,
    unsigned short* __restrict__ kh, unsigned short* __restrict__ kl,
    float* __restrict__ vtmp)
{
  __shared__ unsigned short Ash[2][64 * 64];
  __shared__ unsigned short Wsh[2][64 * 64];

  const int r0 = blockIdx.x * 64;      // M tile
  const int n0 = blockIdx.y * 64;      // N tile (384/64 = 6)
  const int t  = threadIdx.x;
  const int l  = t & 63, w = t >> 6;
  const int wm = w >> 1, wn = w & 1;   // 2x2 wave grid
  const int fr = l & 15, kg = l >> 4;  // fragment row / k-group

  f32x4 acc[2][2] = {};

  for (int k0 = 0; k0 < DM; k0 += 64) {
    #pragma unroll
    for (int i = 0; i < 2; ++i) {
      const int flat = t + i * 256;          // 512 16B segments per tile
      const int row = flat >> 3, sg = flat & 7;
      const int sgs = sg ^ (row & 7);        // pre-swizzled source (T2)
      const size_t ga = (size_t)(r0 + row) * DM + k0 + sgs * 8;
      const size_t gw = (size_t)(n0 + row) * DM + k0 + sgs * 8;
      gload16(Ah + ga, &Ash[0][flat * 8]);
      gload16(Al + ga, &Ash[1][flat * 8]);
      gload16(Wh + gw, &Wsh[0][flat * 8]);
      gload16(Wl + gw, &Wsh[1][flat * 8]);
    }
    __syncthreads();

    #pragma unroll
    for (int kk = 0; kk < 2; ++kk) {
      bf16x8 ah[2], al[2], bh[2], bl[2];
      #pragma unroll
      for (int im = 0; im < 2; ++im) {
        const int row = wm * 32 + im * 16 + fr;
        const int off = row * 64 + ((kk * 4 + kg) ^ (row & 7)) * 8;
        ah[im] = *(const bf16x8*)&Ash[0][off];
        al[im] = *(const bf16x8*)&Ash[1][off];
      }
      #pragma unroll
      for (int in = 0; in < 2; ++in) {
        const int row = wn * 32 + in * 16 + fr;
        const int off = row * 64 + ((kk * 4 + kg) ^ (row & 7)) * 8;
        bh[in] = *(const bf16x8*)&Wsh[0][off];
        bl[in] = *(const bf16x8*)&Wsh[1][off];
      }
      #pragma unroll
      for (int im = 0; im < 2; ++im)
        #pragma unroll
        for (int in = 0; in < 2; ++in) {
          acc[im][in] = __builtin_amdgcn_mfma_f32_16x16x32_bf16(ah[im], bh[in], acc[im][in], 0, 0, 0);
          acc[im][in] = __builtin_amdgcn_mfma_f32_16x16x32_bf16(ah[im], bl[in], acc[im][in], 0, 0, 0);
          acc[im][in] = __builtin_amdgcn_mfma_f32_16x16x32_bf16(al[im], bh[in], acc[im][in], 0, 0, 0);
        }
    }
    __syncthreads();
  }

  // Epilogue: C/D layout col = lane&15, row = (lane>>4)*4 + reg
  const int crow = kg * 4;
  #pragma unroll
  for (int im = 0; im < 2; ++im)
    #pragma unroll
    for (int in = 0; in < 2; ++in) {
      const int n = n0 + wn * 32 + in * 16 + fr;
      const int p = n >> 7, c = n & 127;           // p uniform per block
      #pragma unroll
      for (int r = 0; r < 4; ++r) {
        const int m = r0 + wm * 32 + im * 16 + crow + r;
        const float val = acc[im][in][r];
        if (p == 2) {
          vtmp[(size_t)m * DK + c] = val;
        } else {
          const unsigned short h = f2bf(val);
          const unsigned short lo2 = f2bf(val - bf2f(h));
          unsigned short* hd = p ? kh : qh;
          unsigned short* ld = p ? kl : ql;
          hd[(size_t)m * DK + c] = h;
          ld[(size_t)m * DK + c] = lo2;
        }
      }
    }
}

// ---------------------------------------------------------------------------
// Prep 3: transpose v fp32 [B][S][128] -> vT hi/lo bf16 [B][128][S]
// ---------------------------------------------------------------------------
__global__ __launch_bounds__(256) void cvtv_kernel(
    const float* __restrict__ v, unsigned short* __restrict__ vTh,
    unsigned short* __restrict__ vTl)
{
  const int s0 = blockIdx.x * 64, d0 = blockIdx.y * 64, b = blockIdx.z;
  __shared__ float Ts[64][65];
  const int t = threadIdx.x;
  const int r = t >> 4, c4 = (t & 15) * 4;
  #pragma unroll
  for (int rr = 0; rr < 4; ++rr) {
    const int sl = r + 16 * rr;
    *(float4*)&Ts[sl][c4] =
        *(const float4*)&v[((size_t)b * S + s0 + sl) * DK + d0 + c4];
  }
  __syncthreads();
  const int dl = t >> 2, sq = (t & 3) * 16;
  unsigned short hbuf[16], lbuf[16];
  #pragma unroll
  for (int j = 0; j < 16; ++j) {
    const float val = Ts[sq + j][dl];
    hbuf[j] = f2bf(val);
    lbuf[j] = f2bf(val - bf2f(hbuf[j]));
  }
  const size_t o = (size_t)b * DK * S + (size_t)(d0 + dl) * S + s0 + sq;
  #pragma unroll
  for (int half = 0; half < 2; ++half) {
    *(u16x8*)&vTh[o + half * 8] = *(u16x8*)&hbuf[half * 8];
    *(u16x8*)&vTl[o + half * 8] = *(u16x8*)&lbuf[half * 8];
  }
}

// ---------------------------------------------------------------------------
// Kernel B: column-softmax STATS ONLY. grid (NSP, 32, B); block (sp, qt)
// loops st = sp, sp+NSP, ... <= qt. Q staged once, K per iteration.
// 2 barriers/tile (trailing barrier removed; ordering provided by the next
// iteration's post-stage barrier).
// ---------------------------------------------------------------------------
__global__ __launch_bounds__(256) void stats_mfma(
    const unsigned short* __restrict__ qh, const unsigned short* __restrict__ ql,
    const unsigned short* __restrict__ kh, const unsigned short* __restrict__ kl,
    float* __restrict__ pm, float* __restrict__ ps)
{
  const int sp = blockIdx.x, qt = blockIdx.y, b = blockIdx.z;
  if (sp > qt) return;
  const int q0 = qt * 64;

  __shared__ unsigned short Bsh[64 * 128], Bsl[64 * 128];   // Q stage / K
  __shared__ float SmL[64 * 2], SeL[64 * 2];

  const int t = threadIdx.x;
  const int l = t & 63, w = t >> 6;
  const int wm = w >> 1, wn = w & 1;
  const int fr = l & 15, kg = l >> 4;

  // ---- stage Q once, pull fragments to registers ----
  #pragma unroll
  for (int i = 0; i < 4; ++i) {
    const int flat = t + i * 256;
    const int row = flat >> 4, sg = flat & 15;
    const int sgs = sg ^ (row & 7);
    const size_t gq = (size_t)(b * S + q0 + row) * DK + sgs * 8;
    gload16(qh + gq, &Bsh[flat * 8]);
    gload16(ql + gq, &Bsl[flat * 8]);
  }
  __syncthreads();
  bf16x8 qfh[2][4], qfl[2][4];
  #pragma unroll
  for (int im = 0; im < 2; ++im)
    #pragma unroll
    for (int ks = 0; ks < 4; ++ks) {
      const int row = wm * 32 + im * 16 + fr;
      const int off = row * 128 + ((ks * 4 + kg) ^ (row & 7)) * 8;
      qfh[im][ks] = *(const bf16x8*)&Bsh[off];
      qfl[im][ks] = *(const bf16x8*)&Bsl[off];
    }
  __syncthreads();   // Q reads done before K overwrites

  for (int st = sp; st <= qt; st += NSP) {
    const int s0 = st * 64;

    // ---- stage K ----
    #pragma unroll
    for (int i = 0; i < 4; ++i) {
      const int flat = t + i * 256;
      const int row = flat >> 4, sg = flat & 15;
      const int sgs = sg ^ (row & 7);
      const size_t gk = (size_t)(b * S + s0 + row) * DK + sgs * 8;
      gload16(kh + gk, &Bsh[flat * 8]);
      gload16(kl + gk, &Bsl[flat * 8]);
    }
    __syncthreads();   // K resident; also orders prev SmL reads vs new writes

    // ---- scores (order must match fused_pv exactly) ----
    f32x4 acc[2][2] = {};
    #pragma unroll
    for (int ks = 0; ks < 4; ++ks) {
      bf16x8 bh[2], bl[2];
      #pragma unroll
      for (int in = 0; in < 2; ++in) {
        const int row = wn * 32 + in * 16 + fr;
        const int off = row * 128 + ((ks * 4 + kg) ^ (row & 7)) * 8;
        bh[in] = *(const bf16x8*)&Bsh[off];
        bl[in] = *(const bf16x8*)&Bsl[off];
      }
      #pragma unroll
      for (int im = 0; im < 2; ++im)
        #pragma unroll
        for (int in = 0; in < 2; ++in) {
          acc[im][in] = __builtin_amdgcn_mfma_f32_16x16x32_bf16(qfh[im][ks], bh[in], acc[im][in], 0, 0, 0);
          acc[im][in] = __builtin_amdgcn_mfma_f32_16x16x32_bf16(qfh[im][ks], bl[in], acc[im][in], 0, 0, 0);
          acc[im][in] = __builtin_amdgcn_mfma_f32_16x16x32_bf16(qfl[im][ks], bh[in], acc[im][in], 0, 0, 0);
        }
    }

    // ---- column stats (softmax over q within this 64-row chunk) ----
    const bool diag = (st == qt);
    float Sm_[2], Se_[2];
    #pragma unroll
    for (int in = 0; in < 2; ++in) {
      const int scol = s0 + wn * 32 + in * 16 + fr;
      float m8 = -INFINITY;
      #pragma unroll
      for (int im = 0; im < 2; ++im)
        #pragma unroll
        for (int r = 0; r < 4; ++r) {
          const int q = q0 + wm * 32 + im * 16 + kg * 4 + r;
          if (!diag || q >= scol) m8 = fmaxf(m8, acc[im][in][r] * SCALE);
        }
      float e8 = 0.f;
      if (m8 > -INFINITY) {
        #pragma unroll
        for (int im = 0; im < 2; ++im)
          #pragma unroll
          for (int r = 0; r < 4; ++r) {
            const int q = q0 + wm * 32 + im * 16 + kg * 4 + r;
            if (!diag || q >= scol) e8 += __expf(acc[im][in][r] * SCALE - m8);
          }
      }
      #pragma unroll
      for (int off = 16; off <= 32; off <<= 1) {
        const float om = __shfl_xor(m8, off);
        const float oe = __shfl_xor(e8, off);
        const float nm = fmaxf(m8, om);
        float ne = 0.f;
        if (m8 > -INFINITY) ne += e8 * __expf(m8 - nm);
        if (om > -INFINITY) ne += oe * __expf(om - nm);
        m8 = nm; e8 = ne;
      }
      Sm_[in] = m8; Se_[in] = e8;
    }
    if (l < 16) {
      #pragma unroll
      for (int in = 0; in < 2; ++in) {
        const int col = wn * 32 + in * 16 + l;
        SmL[col * 2 + wm] = Sm_[in];
        SeL[col * 2 + wm] = Se_[in];
      }
    }
    __syncthreads();
    if (t < 64) {
      const float m0 = SmL[t * 2 + 0], m1 = SmL[t * 2 + 1];
      const float nm = fmaxf(m0, m1);
      float ne = 0.f;
      if (m0 > -INFINITY) ne += SeL[t * 2 + 0] * __expf(m0 - nm);
      if (m1 > -INFINITY) ne += SeL[t * 2 + 1] * __expf(m1 - nm);
      const size_t o = ((size_t)(b * 32 + qt)) * S + s0 + t;
      pm[o] = nm;
      ps[o] = ne;
    }
    // no trailing barrier: the next iteration's post-stage barrier orders
    // SmL reads before the next SmL writes; pm/ps stores drain there too.
  }
}

// ---------------------------------------------------------------------------
// Kernel C: combine 32 row-chunk partials -> per-column max m and 1/sum.
// ---------------------------------------------------------------------------
__global__ void colcombine_kernel(const float* __restrict__ pm, const float* __restrict__ ps,
                                  float* __restrict__ cm, float* __restrict__ cinv)
{
  const int s = blockIdx.x * 256 + threadIdx.x;
  const int b = blockIdx.y;
  const int ch0 = s >> 6;
  float m = -INFINITY;
  for (int ch = ch0; ch < 32; ++ch)
    m = fmaxf(m, pm[((size_t)(b * 32 + ch)) * S + s]);
  float sum = 0.f;
  for (int ch = ch0; ch < 32; ++ch) {
    const size_t i = ((size_t)(b * 32 + ch)) * S + s;
    sum += ps[i] * __expf(pm[i] - m);
  }
  cm[(size_t)b * S + s]   = m;
  cinv[(size_t)b * S + s] = 1.f / sum;   // sum >= 1 (diagonal element)
}

// ---------------------------------------------------------------------------
// zero out (out is atomically accumulated)
// ---------------------------------------------------------------------------
__global__ void zero_out_kernel(float* __restrict__ out)
{
  const size_t idx = (size_t)blockIdx.x * 256 + threadIdx.x;
  ((float4*)out)[idx] = float4{0.f, 0.f, 0.f, 0.f};
}

// ---------------------------------------------------------------------------
// Kernel D: fused second pass. grid (NSP, 32, B); block (sp, qt) loops
// st = sp, sp+NSP, ... <= qt, accumulating PV in registers; one atomic
// epilogue per block. att/mirror stores are DEFERRED one tile and issued in
// the next tile's K/V-load shadow, so the expensive vmcnt drain covers loads
// and stores together; the other two barriers have no outstanding VMEM.
// Scores recomputed bitwise-identical to stats_mfma. LDS 72 KB.
// ---------------------------------------------------------------------------
__global__ __launch_bounds__(256) void fused_pv(
    const unsigned short* __restrict__ qh, const unsigned short* __restrict__ ql,
    const unsigned short* __restrict__ kh, const unsigned short* __restrict__ kl,
    const unsigned short* __restrict__ vTh, const unsigned short* __restrict__ vTl,
    const float* __restrict__ cm, const float* __restrict__ cinv,
    float* __restrict__ att, float* __restrict__ out)
{
  const int sp = blockIdx.x, qt = blockIdx.y, b = blockIdx.z;
  if (sp > qt) return;
  const int q0 = qt * 64;
  float* attb = att + (size_t)b * S * S;
  const unsigned short* vth = vTh + (size_t)b * DK * S;
  const unsigned short* vtl = vTl + (size_t)b * DK * S;

  __shared__ unsigned short Ksh[64 * 128], Ksl[64 * 128];   // Q stage / K (32 KB)
  __shared__ unsigned short Vsh[128 * 64], Vsl[128 * 64];   // vT tile (32 KB)
  __shared__ unsigned short Psh[64 * 64];                   // P tile (8 KB)

  const int t = threadIdx.x;
  const int l = t & 63, w = t >> 6;
  const int wm = w >> 1, wn = w & 1;          // 2x2 wave grid (scores)
  const int fr = l & 15, kg = l >> 4;

  // ---- stage Q tile once, pull fragments to registers ----
  #pragma unroll
  for (int i = 0; i < 4; ++i) {
    const int flat = t + i * 256;
    const int row = flat >> 4, sg = flat & 15;
    const int sgs = sg ^ (row & 7);
    const size_t gq = (size_t)(b * S + q0 + row) * DK + sgs * 8;
    gload16(qh + gq, &Ksh[flat * 8]);
    gload16(ql + gq, &Ksl[flat * 8]);
  }
  __syncthreads();
  bf16x8 qfh[2][4], qfl[2][4];
  #pragma unroll
  for (int im = 0; im < 2; ++im)
    #pragma unroll
    for (int ks = 0; ks < 4; ++ks) {
      const int row = wm * 32 + im * 16 + fr;
      const int off = row * 128 + ((ks * 4 + kg) ^ (row & 7)) * 8;
      qfh[im][ks] = *(const bf16x8*)&Ksh[off];
      qfl[im][ks] = *(const bf16x8*)&Ksl[off];
    }
  __syncthreads();   // all Q reads done before K overwrites

  f32x4 acc[8] = {};     // PV accumulator, persists across st tiles
  float xv[2][2][4];     // previous tile's normalized att values
  int prev_s0 = -1;
  int prev_mirror = 0;

  for (int st = sp; st <= qt; st += NSP) {
    const int s0 = st * 64;

    // ---- stage K AND V tiles (issue) ----
    #pragma unroll
    for (int i = 0; i < 4; ++i) {
      const int flat = t + i * 256;
      const int row = flat >> 4, sg = flat & 15;
      const int sgs = sg ^ (row & 7);
      const size_t gk = (size_t)(b * S + s0 + row) * DK + sgs * 8;
      gload16(kh + gk, &Ksh[flat * 8]);
      gload16(kl + gk, &Ksl[flat * 8]);
    }
    #pragma unroll
    for (int i = 0; i < 4; ++i) {
      const int flat = t + i * 256;
      const int row = flat >> 3, sg = flat & 7;
      const int sgs = sg ^ (row & 7);
      const size_t gv = (size_t)row * S + s0 + sgs * 8;
      gload16(vth + gv, &Vsh[flat * 8]);
      gload16(vtl + gv, &Vsl[flat * 8]);
    }

    // ---- deferred att/mirror stores for the PREVIOUS tile (load shadow) ----
    if (prev_s0 >= 0) {
      if (prev_mirror) {
        const f32x4 z = {0.f, 0.f, 0.f, 0.f};
        #pragma unroll
        for (int i = 0; i < 4; ++i) {
          const int flat = t + i * 256;
          const int row = flat >> 4, c4 = (flat & 15) * 4;
          __builtin_nontemporal_store(z, (f32x4*)&attb[(size_t)(prev_s0 + row) * S + q0 + c4]);
        }
      }
      #pragma unroll
      for (int im = 0; im < 2; ++im)
        #pragma unroll
        for (int in = 0; in < 2; ++in) {
          const int sloc = wn * 32 + in * 16 + fr;
          #pragma unroll
          for (int r = 0; r < 4; ++r) {
            const int qloc = wm * 32 + im * 16 + kg * 4 + r;
            __builtin_nontemporal_store(xv[im][in][r],
                                        &attb[(size_t)(q0 + qloc) * S + prev_s0 + sloc]);
          }
        }
    }
    __syncthreads();   // joint drain: K/V loads + deferred stores

    // ---- scores: identical accumulation order to stats_mfma ----
    f32x4 sacc[2][2] = {};
    #pragma unroll
    for (int ks = 0; ks < 4; ++ks) {
      bf16x8 bh[2], bl[2];
      #pragma unroll
      for (int in = 0; in < 2; ++in) {
        const int row = wn * 32 + in * 16 + fr;
        const int off = row * 128 + ((ks * 4 + kg) ^ (row & 7)) * 8;
        bh[in] = *(const bf16x8*)&Ksh[off];
        bl[in] = *(const bf16x8*)&Ksl[off];
      }
      #pragma unroll
      for (int im = 0; im < 2; ++im)
        #pragma unroll
        for (int in = 0; in < 2; ++in) {
          sacc[im][in] = __builtin_amdgcn_mfma_f32_16x16x32_bf16(qfh[im][ks], bh[in], sacc[im][in], 0, 0, 0);
          sacc[im][in] = __builtin_amdgcn_mfma_f32_16x16x32_bf16(qfh[im][ks], bl[in], sacc[im][in], 0, 0, 0);
          sacc[im][in] = __builtin_amdgcn_mfma_f32_16x16x32_bf16(qfl[im][ks], bh[in], sacc[im][in], 0, 0, 0);
        }
    }

    // ---- normalize in-register; P (plain bf16) -> LDS; keep xv in regs ----
    const bool diag = (st == qt);
    #pragma unroll
    for (int in = 0; in < 2; ++in) {
      const int sloc = wn * 32 + in * 16 + fr;
      const int scol = s0 + sloc;
      const float m   = cm[(size_t)b * S + scol];
      const float inv = cinv[(size_t)b * S + scol];
      #pragma unroll
      for (int im = 0; im < 2; ++im) {
        #pragma unroll
        for (int r = 0; r < 4; ++r) {
          const int qloc = wm * 32 + im * 16 + kg * 4 + r;
          const bool live = !diag || (q0 + qloc >= scol);
          const float x = live ? __expf(sacc[im][in][r] * SCALE - m) * inv : 0.f;
          xv[im][in][r] = x;
          const int idx = qloc * 64 + (((sloc >> 3) ^ (qloc & 7)) * 8 + (sloc & 7));
          Psh[idx] = f2bf(x);
        }
      }
    }
    __syncthreads();   // P visible (no outstanding VMEM here — cheap)

    // ---- PV: wave w computes q rows [w*16, w*16+16), all 128 d cols ----
    #pragma unroll
    for (int ks2 = 0; ks2 < 2; ++ks2) {
      const int arow = w * 16 + fr;
      const int aoff = arow * 64 + ((ks2 * 4 + kg) ^ (arow & 7)) * 8;
      const bf16x8 a = *(const bf16x8*)&Psh[aoff];
      #pragma unroll
      for (int in = 0; in < 8; ++in) {
        const int brow = in * 16 + fr;
        const int boff = brow * 64 + ((ks2 * 4 + kg) ^ (brow & 7)) * 8;
        const bf16x8 b_h = *(const bf16x8*)&Vsh[boff];
        const bf16x8 b_l = *(const bf16x8*)&Vsl[boff];
        acc[in] = __builtin_amdgcn_mfma_f32_16x16x32_bf16(a, b_h, acc[in], 0, 0, 0);
        acc[in] = __builtin_amdgcn_mfma_f32_16x16x32_bf16(a, b_l, acc[in], 0, 0, 0);
      }
    }
    __syncthreads();   // LDS reads done before next-iter staging (cheap)

    prev_s0 = s0;
    prev_mirror = (st < qt) ? 1 : 0;
  }

  // ---- final tile's deferred stores ----
  if (prev_s0 >= 0) {
    if (prev_mirror) {
      const f32x4 z = {0.f, 0.f, 0.f, 0.f};
      #pragma unroll
      for (int i = 0; i < 4; ++i) {
        const int flat = t + i * 256;
        const int row = flat >> 4, c4 = (flat & 15) * 4;
        __builtin_nontemporal_store(z, (f32x4*)&attb[(size_t)(prev_s0 + row) * S + q0 + c4]);
      }
    }
    #pragma unroll
    for (int im = 0; im < 2; ++im)
      #pragma unroll
      for (int in = 0; in < 2; ++in) {
        const int sloc = wn * 32 + in * 16 + fr;
        #pragma unroll
        for (int r = 0; r < 4; ++r) {
          const int qloc = wm * 32 + im * 16 + kg * 4 + r;
          __builtin_nontemporal_store(xv[im][in][r],
                                      &attb[(size_t)(q0 + qloc) * S + prev_s0 + sloc]);
        }
      }
  }

  // ---- single atomic epilogue per block ----
  #pragma unroll
  for (int in = 0; in < 8; ++in) {
    #pragma unroll
    for (int r = 0; r < 4; ++r) {
      const int q = q0 + w * 16 + kg * 4 + r;
      const int d = in * 16 + fr;
      atomicAdd(&out[((size_t)b * S + q) * DK + d], acc[in][r]);
    }
  }
}

// ---------------------------------------------------------------------------
extern "C" void kernel_launch(void* const* d_in, const int* in_sizes, int n_in,
                              void* d_out, int out_size, void* d_ws, size_t ws_size,
                              hipStream_t stream)
{
  const float* vin = (const float*)d_in[0];
  const float* wq  = (const float*)d_in[1];
  const float* wk  = (const float*)d_in[2];
  const float* wv  = (const float*)d_in[3];

  float* out = (float*)d_out;
  float* att = out + (size_t)B * S * DK;     // attention output region (64 MB)

  // bf16 copies of vin / W live INSIDE the att region (dead before att writes)
  unsigned short* Ah  = (unsigned short*)att;
  unsigned short* Al  = Ah  + (size_t)BS * DM;
  unsigned short* Wth = Al  + (size_t)BS * DM;
  unsigned short* Wtl = Wth + (size_t)384 * DM;

  constexpr size_t NE = (size_t)BS * DK;     // 1048576
  unsigned short* qh  = (unsigned short*)d_ws;
  unsigned short* ql  = qh  + NE;
  unsigned short* kh  = ql  + NE;
  unsigned short* kl  = kh  + NE;
  unsigned short* vTh = kl  + NE;
  unsigned short* vTl = vTh + NE;
  float* vtmp = (float*)(vTl + NE);          // 4 MB
  float* pm   = vtmp;                        // aliases vtmp (v dead by then)
  float* ps   = pm + 32ull * B * S;          // 1 MB each
  float* cm   = ps + 32ull * B * S;
  float* cinv = cm + (size_t)B * S;

  cvt_hilo         <<<dim3(BS * DM / 1024),  256, 0, stream>>>(vin, Ah, Al);
  cvtw_kernel      <<<dim3(384),             256, 0, stream>>>(wq, wk, wv, Wth, Wtl);
  proj_mfma        <<<dim3(128, 6),          256, 0, stream>>>(Ah, Al, Wth, Wtl,
                                                               qh, ql, kh, kl, vtmp);
  cvtv_kernel      <<<dim3(S / 64, 2, B),    256, 0, stream>>>(vtmp, vTh, vTl);
  zero_out_kernel  <<<dim3(BS * DK / 1024),  256, 0, stream>>>(out);
  stats_mfma       <<<dim3(NSP, 32, B),      256, 0, stream>>>(qh, ql, kh, kl, pm, ps);
  colcombine_kernel<<<dim3(S / 256, B),      256, 0, stream>>>(pm, ps, cm, cinv);
  fused_pv         <<<dim3(NSP, 32, B),      256, 0, stream>>>(qh, ql, kh, kl, vTh, vTl,
                                                               cm, cinv, att, out);
}